// Round 1
// baseline (960.507 us; speedup 1.0000x reference)
//
#include <hip/hip_runtime.h>

// ---------------------------------------------------------------------------
// MiniMax Lightning Attention (B=2,N=2048,D=2048,H=16,HD=128), fp32 in/out.
// Pipeline: cast->bf16 | GEMM qkv(silu) | GEMM gate(sigmoid) | chunked linear
// attention scan (C=128) | RMSNorm*gate | GEMM out.
// ---------------------------------------------------------------------------

typedef __attribute__((ext_vector_type(8))) short short8;
typedef __attribute__((ext_vector_type(4))) float f32x4;

__device__ __forceinline__ float blo(unsigned int u){ return __uint_as_float(u << 16); }
__device__ __forceinline__ float bhi(unsigned int u){ return __uint_as_float(u & 0xffff0000u); }
__device__ __forceinline__ float b2f(unsigned short v){ return __uint_as_float(((unsigned int)v) << 16); }
__device__ __forceinline__ unsigned short f2b(float f){
  unsigned int u = __float_as_uint(f);
  return (unsigned short)((u + 0x7fffu + ((u >> 16) & 1u)) >> 16);
}

#define GLOAD_LDS16(g, l) __builtin_amdgcn_global_load_lds( \
    (const __attribute__((address_space(1))) unsigned int*)(g), \
    (__attribute__((address_space(3))) unsigned int*)(l), 16, 0, 0)

// ---------------- workspace layout (bytes) ----------------
#define OFF_XB     ((size_t)0)           // x bf16            [4096][2048]
#define OFF_WQKVB  ((size_t)16777216)    // w_qkv bf16        [6144][2048]
#define OFF_WGATEB ((size_t)41943040)    // w_gate bf16       [2048][2048]
#define OFF_WOUTB  ((size_t)50331648)    // w_out bf16        [2048][2048]
#define OFF_QB     ((size_t)58720256)    // q bf16            [B][H][N][HD]
#define OFF_KB     ((size_t)75497472)    // k bf16
#define OFF_VB     ((size_t)92274688)    // v bf16
#define OFF_KVC    ((size_t)109051904)   // chunk KV / states f32 [B][H][16][128][128]
#define OFF_ATTN   ((size_t)142606336)   // attn out f32      [B][N][2048]
#define OFF_GATE   ((size_t)176160768)   // sigmoid gate bf16 [4096][2048]
#define OFF_YBUF   ((size_t)192937984)   // normed*gated bf16 [4096][2048]
#define WS_NEED    ((size_t)209715200)

// ---------------- fp32 -> bf16 cast ----------------
__global__ __launch_bounds__(256)
void cast_f2b(const float* __restrict__ in, unsigned short* __restrict__ o, int n)
{
  int idx = (blockIdx.x * 256 + threadIdx.x) * 4;
  if (idx >= n) return;
  float4 v = *(const float4*)&in[idx];
  ushort4 u;
  u.x = f2b(v.x); u.y = f2b(v.y); u.z = f2b(v.z); u.w = f2b(v.w);
  *(ushort4*)&o[idx] = u;
}

// ---------------- bf16 GEMM: C[M,N] = A[M,K] * B[N,K]^T ----------------
// 128x128 tile, BK=32, 4 waves, 4x4 16x16x32 frags per wave (m97 structure).
// EPI 0: write f32 C to o0 (ld=Nn)
// EPI 1: silu, scatter to q/k/v bf16 [B][H][N][HD] (o0,o1,o2)
// EPI 2: sigmoid, write bf16 to o0 (ld=Nn)
template<int EPI>
__global__ __launch_bounds__(256)
void gemm_bt(const unsigned short* __restrict__ A, const unsigned short* __restrict__ Bm,
             int K, int Nn, void* __restrict__ o0, void* __restrict__ o1, void* __restrict__ o2)
{
  __shared__ unsigned short As[4096];
  __shared__ unsigned short Bs[4096];
  const int tid  = threadIdx.x;
  const int lane = tid & 63, w = tid >> 6;
  const int mBase = blockIdx.y << 7, nBase = blockIdx.x << 7;

  f32x4 zero = {0.f, 0.f, 0.f, 0.f};
  f32x4 acc[4][4];
#pragma unroll
  for (int m = 0; m < 4; ++m)
#pragma unroll
    for (int n = 0; n < 4; ++n) acc[m][n] = zero;

  const int wr = w >> 1, wc = w & 1;
  const int rA = (wr << 6) + (lane & 15);
  const int cB = (wc << 6) + (lane & 15);
  const int kg = (lane >> 4) << 3;
  const int segBase = w << 7;              // w*128 segments of 16B
  const int nIter = K >> 5;

  for (int kt = 0; kt < nIter; ++kt) {
    const int k0 = kt << 5;
#pragma unroll
    for (int rep = 0; rep < 2; ++rep) {
      int seg = segBase + (rep << 6) + lane;     // 0..511
      int r  = seg >> 2;
      int c8 = (seg & 3) << 3;
      GLOAD_LDS16(A  + ((size_t)(mBase + r) * K + k0 + c8), &As[(segBase + (rep << 6)) << 3]);
      GLOAD_LDS16(Bm + ((size_t)(nBase + r) * K + k0 + c8), &Bs[(segBase + (rep << 6)) << 3]);
    }
    __syncthreads();   // drains vmcnt before barrier (compiler-inserted)
    short8 af[4], bfv[4];
#pragma unroll
    for (int m = 0; m < 4; ++m) af[m]  = *(const short8*)&As[((rA + (m << 4)) << 5) + kg];
#pragma unroll
    for (int n = 0; n < 4; ++n) bfv[n] = *(const short8*)&Bs[((cB + (n << 4)) << 5) + kg];
#pragma unroll
    for (int m = 0; m < 4; ++m)
#pragma unroll
      for (int n = 0; n < 4; ++n)
        acc[m][n] = __builtin_amdgcn_mfma_f32_16x16x32_bf16(af[m], bfv[n], acc[m][n], 0, 0, 0);
    __syncthreads();
  }

  // epilogue: C/D layout col = lane&15, row = (lane>>4)*4 + reg  [m89-verified]
#pragma unroll
  for (int m = 0; m < 4; ++m) {
#pragma unroll
    for (int n = 0; n < 4; ++n) {
      const int row0 = mBase + (wr << 6) + (m << 4) + ((lane >> 4) << 2);
      const int col  = nBase + (wc << 6) + (n << 4) + (lane & 15);
      f32x4 v = acc[m][n];
#pragma unroll
      for (int i2 = 0; i2 < 4; ++i2) {
        const int row = row0 + i2;
        float val = v[i2];
        if (EPI == 0) {
          ((float*)o0)[(size_t)row * Nn + col] = val;
        } else if (EPI == 1) {
          float sv = val / (1.f + __expf(-val));       // silu
          int hh = col / 384;
          int r3 = col - hh * 384;
          int which = r3 >> 7;
          int dd = r3 & 127;
          int bb = row >> 11, nn = row & 2047;
          unsigned short* dst = (which == 0) ? (unsigned short*)o0
                              : (which == 1) ? (unsigned short*)o1
                                             : (unsigned short*)o2;
          dst[(((size_t)(bb * 16 + hh) << 11) + nn) * 128 + dd] = f2b(sv);
        } else {
          float sg = 1.f / (1.f + __expf(-val));       // sigmoid
          ((unsigned short*)o0)[(size_t)row * Nn + col] = f2b(sg);
        }
      }
    }
  }
}

// ---------------- per-chunk local KV: KVc = sum_j lam^(127-j) k_j v_j^T ----------------
__global__ __launch_bounds__(256)
void chunk_kv(const unsigned short* __restrict__ kq, const unsigned short* __restrict__ vq,
              const float* __restrict__ slope, float* __restrict__ KVc)
{
  const int blk = blockIdx.x;                 // ((b*16+h)*16 + c)
  const int cc = blk & 15, h = (blk >> 4) & 15;
  const int tid = threadIdx.x;
  __shared__ unsigned short Ks[16384], Vs[16384];
  const size_t base = ((size_t)(blk >> 4) << 18) + ((size_t)cc << 14);
#pragma unroll
  for (int it = 0; it < 8; ++it) {
    int e8 = (it * 256 + tid) * 8;
    *(uint4*)&Ks[e8] = *(const uint4*)&kq[base + e8];
    *(uint4*)&Vs[e8] = *(const uint4*)&vq[base + e8];
  }
  __syncthreads();
  const float lam = __expf(-slope[h]);
  float acc[8][8];
#pragma unroll
  for (int a = 0; a < 8; ++a)
#pragma unroll
    for (int b2 = 0; b2 < 8; ++b2) acc[a][b2] = 0.f;
  const int tr = (tid >> 4) << 3, tc = (tid & 15) << 3;
  float wj = 1.f;                              // lam^(127-j), j descending
  for (int j = 127; j >= 0; --j) {
    uint4 kk = *(const uint4*)&Ks[j * 128 + tr];
    uint4 vv = *(const uint4*)&Vs[j * 128 + tc];
    float kf[8], vf[8];
    kf[0]=blo(kk.x); kf[1]=bhi(kk.x); kf[2]=blo(kk.y); kf[3]=bhi(kk.y);
    kf[4]=blo(kk.z); kf[5]=bhi(kk.z); kf[6]=blo(kk.w); kf[7]=bhi(kk.w);
    vf[0]=blo(vv.x); vf[1]=bhi(vv.x); vf[2]=blo(vv.y); vf[3]=bhi(vv.y);
    vf[4]=blo(vv.z); vf[5]=bhi(vv.z); vf[6]=blo(vv.w); vf[7]=bhi(vv.w);
#pragma unroll
    for (int a = 0; a < 8; ++a) kf[a] *= wj;
#pragma unroll
    for (int a = 0; a < 8; ++a)
#pragma unroll
      for (int b2 = 0; b2 < 8; ++b2) acc[a][b2] += kf[a] * vf[b2];
    wj *= lam;
  }
  float* outp = KVc + ((size_t)blk << 14);
#pragma unroll
  for (int a = 0; a < 8; ++a) {
    *(float4*)&outp[(tr + a) * 128 + tc]     = make_float4(acc[a][0], acc[a][1], acc[a][2], acc[a][3]);
    *(float4*)&outp[(tr + a) * 128 + tc + 4] = make_float4(acc[a][4], acc[a][5], acc[a][6], acc[a][7]);
  }
}

// ---------------- sequential chunk combine (in-place: KVc[c] <- state BEFORE chunk c) ----
__global__ __launch_bounds__(256)
void combine_kv(float* __restrict__ KVc, const float* __restrict__ past_kv,
                const float* __restrict__ slope, float* __restrict__ outkv)
{
  const int bh = blockIdx.x;                  // b*16+h
  const int h = bh & 15;
  const int tid = threadIdx.x;
  const float lamC = __expf(-slope[h] * 128.f);
  float S[64];
  const float* pp = past_kv + ((size_t)bh << 14);
#pragma unroll
  for (int i = 0; i < 64; ++i) S[i] = pp[i * 256 + tid];
  for (int cc = 0; cc < 16; ++cc) {
    float* p = KVc + ((((size_t)bh << 4) + cc) << 14);
#pragma unroll
    for (int i = 0; i < 64; ++i) {
      float t = p[i * 256 + tid];
      p[i * 256 + tid] = S[i];                // state before chunk cc
      S[i] = lamC * S[i] + t;
    }
  }
  float* op = outkv + ((size_t)bh << 14);
#pragma unroll
  for (int i = 0; i < 64; ++i) op[i * 256 + tid] = S[i];   // kv_final
}

// ---------------- per-chunk outputs ----------------
// o_i = lam^{i+1} q_i . S  +  sum_{j<=i} lam^{i-j} (q_i . k_j) v_j
__global__ __launch_bounds__(256)
void chunk_out(const unsigned short* __restrict__ qg, const unsigned short* __restrict__ kgl,
               const unsigned short* __restrict__ vg, const float* __restrict__ States,
               const float* __restrict__ slope, float* __restrict__ attn)
{
  const int blk = blockIdx.x;
  const int cc = blk & 15, h = (blk >> 4) & 15, b = blk >> 8;
  const int tid = threadIdx.x;
  __shared__ unsigned short Qs[16384], Ks[16384], Vs[16384], Ss[16384];  // 128 KiB
  const size_t base = ((size_t)(blk >> 4) << 18) + ((size_t)cc << 14);
#pragma unroll
  for (int it = 0; it < 8; ++it) {
    int e8 = (it * 256 + tid) * 8;
    *(uint4*)&Qs[e8] = *(const uint4*)&qg[base + e8];
    *(uint4*)&Ks[e8] = *(const uint4*)&kgl[base + e8];
    *(uint4*)&Vs[e8] = *(const uint4*)&vg[base + e8];
  }
  const float* Sg = States + ((size_t)blk << 14);
#pragma unroll
  for (int it = 0; it < 16; ++it) {
    int e = (it * 256 + tid) * 4;
    float4 sv = *(const float4*)&Sg[e];
    ushort4 u;
    u.x = f2b(sv.x); u.y = f2b(sv.y); u.z = f2b(sv.z); u.w = f2b(sv.w);
    *(ushort4*)&Ss[e] = u;
  }
  __syncthreads();
  const float s = slope[h];
  const int i  = tid >> 1;            // output row within chunk
  const int dh = (tid & 1) << 6;      // d-column half
  float o[64];
#pragma unroll
  for (int d = 0; d < 64; ++d) o[d] = 0.f;

  // inter-chunk part
  const float lami1 = __expf(-s * (float)(i + 1));
  for (int e = 0; e < 128; ++e) {
    float qe = b2f(Qs[i * 128 + e]) * lami1;
#pragma unroll
    for (int d8 = 0; d8 < 8; ++d8) {
      uint4 ss = *(const uint4*)&Ss[e * 128 + dh + d8 * 8];
      o[d8*8+0] += qe * blo(ss.x); o[d8*8+1] += qe * bhi(ss.x);
      o[d8*8+2] += qe * blo(ss.y); o[d8*8+3] += qe * bhi(ss.y);
      o[d8*8+4] += qe * blo(ss.z); o[d8*8+5] += qe * bhi(ss.z);
      o[d8*8+6] += qe * blo(ss.w); o[d8*8+7] += qe * bhi(ss.w);
    }
  }

  // intra-chunk part
  uint4 qv[16];
#pragma unroll
  for (int t8 = 0; t8 < 16; ++t8) qv[t8] = *(const uint4*)&Qs[i * 128 + t8 * 8];
  for (int j = 0; j <= i; ++j) {
    float p = 0.f;
#pragma unroll
    for (int t8 = 0; t8 < 16; ++t8) {
      uint4 kk = *(const uint4*)&Ks[j * 128 + t8 * 8];      // wave-uniform -> broadcast
      p += blo(qv[t8].x)*blo(kk.x) + bhi(qv[t8].x)*bhi(kk.x)
         + blo(qv[t8].y)*blo(kk.y) + bhi(qv[t8].y)*bhi(kk.y)
         + blo(qv[t8].z)*blo(kk.z) + bhi(qv[t8].z)*bhi(kk.z)
         + blo(qv[t8].w)*blo(kk.w) + bhi(qv[t8].w)*bhi(kk.w);
    }
    p *= __expf(-s * (float)(i - j));
#pragma unroll
    for (int d8 = 0; d8 < 8; ++d8) {
      uint4 vv = *(const uint4*)&Vs[j * 128 + dh + d8 * 8];
      o[d8*8+0] += p * blo(vv.x); o[d8*8+1] += p * bhi(vv.x);
      o[d8*8+2] += p * blo(vv.y); o[d8*8+3] += p * bhi(vv.y);
      o[d8*8+4] += p * blo(vv.z); o[d8*8+5] += p * bhi(vv.z);
      o[d8*8+6] += p * blo(vv.w); o[d8*8+7] += p * bhi(vv.w);
    }
  }
  // attn[b*2048 + cc*128 + i][h*128 + dh + d]
  float* orow = attn + ((size_t)((b << 11) + (cc << 7) + i) << 11) + (h << 7) + dh;
#pragma unroll
  for (int d4 = 0; d4 < 16; ++d4)
    *(float4*)&orow[d4 * 4] = make_float4(o[d4*4], o[d4*4+1], o[d4*4+2], o[d4*4+3]);
}

// ---------------- RMSNorm * norm_w * sigmoid-gate -> bf16 ----------------
__global__ __launch_bounds__(256)
void norm_gate(const float* __restrict__ attn, const unsigned short* __restrict__ gateb,
               const float* __restrict__ normw, unsigned short* __restrict__ ybuf)
{
  const int row = blockIdx.x;
  const int tid = threadIdx.x;
  const float* ar = attn + ((size_t)row << 11);
  float4 v0 = *(const float4*)&ar[tid * 8];
  float4 v1 = *(const float4*)&ar[tid * 8 + 4];
  float ss = v0.x*v0.x + v0.y*v0.y + v0.z*v0.z + v0.w*v0.w
           + v1.x*v1.x + v1.y*v1.y + v1.z*v1.z + v1.w*v1.w;
#pragma unroll
  for (int off = 32; off > 0; off >>= 1) ss += __shfl_down(ss, off);
  __shared__ float red[4];
  if ((tid & 63) == 0) red[tid >> 6] = ss;
  __syncthreads();
  float tot = red[0] + red[1] + red[2] + red[3];
  float scale = rsqrtf(tot * (1.f / 2048.f) + 1e-6f);
  uint4 gg = *(const uint4*)&gateb[((size_t)row << 11) + tid * 8];
  float4 w0 = *(const float4*)&normw[tid * 8];
  float4 w1 = *(const float4*)&normw[tid * 8 + 4];
  ushort4 o0, o1;
  o0.x = f2b(v0.x * scale * w0.x * blo(gg.x));
  o0.y = f2b(v0.y * scale * w0.y * bhi(gg.x));
  o0.z = f2b(v0.z * scale * w0.z * blo(gg.y));
  o0.w = f2b(v0.w * scale * w0.w * bhi(gg.y));
  o1.x = f2b(v1.x * scale * w1.x * blo(gg.z));
  o1.y = f2b(v1.y * scale * w1.y * bhi(gg.z));
  o1.z = f2b(v1.z * scale * w1.z * blo(gg.w));
  o1.w = f2b(v1.w * scale * w1.w * bhi(gg.w));
  *(ushort4*)&ybuf[((size_t)row << 11) + tid * 8]     = o0;
  *(ushort4*)&ybuf[((size_t)row << 11) + tid * 8 + 4] = o1;
}

// ---------------------------------------------------------------------------
extern "C" void kernel_launch(void* const* d_in, const int* in_sizes, int n_in,
                              void* d_out, int out_size, void* d_ws, size_t ws_size,
                              hipStream_t stream)
{
  const float* x       = (const float*)d_in[0];
  const float* past_kv = (const float*)d_in[1];
  const float* slope   = (const float*)d_in[2];
  const float* w_qkv   = (const float*)d_in[3];
  const float* w_gate  = (const float*)d_in[4];
  const float* w_out   = (const float*)d_in[5];
  const float* norm_w  = (const float*)d_in[6];
  float* out    = (float*)d_out;
  float* out_kv = out + 8388608;          // [B,H,HD,HD] region of d_out
  if (ws_size < WS_NEED) return;
  char* ws = (char*)d_ws;
  unsigned short* xb     = (unsigned short*)(ws + OFF_XB);
  unsigned short* wqkvb  = (unsigned short*)(ws + OFF_WQKVB);
  unsigned short* wgateb = (unsigned short*)(ws + OFF_WGATEB);
  unsigned short* woutb  = (unsigned short*)(ws + OFF_WOUTB);
  unsigned short* qb     = (unsigned short*)(ws + OFF_QB);
  unsigned short* kb     = (unsigned short*)(ws + OFF_KB);
  unsigned short* vb     = (unsigned short*)(ws + OFF_VB);
  float*          kvc    = (float*)(ws + OFF_KVC);
  float*          attn   = (float*)(ws + OFF_ATTN);
  unsigned short* gate   = (unsigned short*)(ws + OFF_GATE);
  unsigned short* ybuf   = (unsigned short*)(ws + OFF_YBUF);

  cast_f2b<<<8192,  256, 0, stream>>>(x,      xb,     8388608);
  cast_f2b<<<12288, 256, 0, stream>>>(w_qkv,  wqkvb,  12582912);
  cast_f2b<<<4096,  256, 0, stream>>>(w_gate, wgateb, 4194304);
  cast_f2b<<<4096,  256, 0, stream>>>(w_out,  woutb,  4194304);

  gemm_bt<1><<<dim3(48, 32), 256, 0, stream>>>(xb, wqkvb, 2048, 6144, qb, kb, vb);
  gemm_bt<2><<<dim3(16, 32), 256, 0, stream>>>(xb, wgateb, 2048, 2048, gate, nullptr, nullptr);

  chunk_kv  <<<512, 256, 0, stream>>>(kb, vb, slope, kvc);
  combine_kv<<<32,  256, 0, stream>>>(kvc, past_kv, slope, out_kv);
  chunk_out <<<512, 256, 0, stream>>>(qb, kb, vb, kvc, slope, attn);

  norm_gate <<<4096, 256, 0, stream>>>(attn, gate, norm_w, ybuf);
  gemm_bt<0><<<dim3(16, 32), 256, 0, stream>>>(ybuf, woutb, 2048, 2048, out, nullptr, nullptr);
}

// Round 2
// 519.412 us; speedup vs baseline: 1.8492x; 1.8492x over previous
//
#include <hip/hip_runtime.h>

// ---------------------------------------------------------------------------
// MiniMax Lightning Attention (B=2,N=2048,D=2048,H=16,HD=128), fp32 in/out.
// cast->bf16 | GEMM qkv(silu, scatter q/k/kTlam/vT) | GEMM gate(sigmoid) |
// MFMA chunk_kv (states transposed) | combine | MFMA chunk_out | norm*gate |
// GEMM out.
// ---------------------------------------------------------------------------

typedef __attribute__((ext_vector_type(8))) short short8;
typedef __attribute__((ext_vector_type(4))) float f32x4;

__device__ __forceinline__ float blo(unsigned int u){ return __uint_as_float(u << 16); }
__device__ __forceinline__ float bhi(unsigned int u){ return __uint_as_float(u & 0xffff0000u); }
__device__ __forceinline__ unsigned short f2b(float f){
  unsigned int u = __float_as_uint(f);
  return (unsigned short)((u + 0x7fffu + ((u >> 16) & 1u)) >> 16);
}
__device__ __forceinline__ unsigned int pk2(float a, float b){
  return (unsigned int)f2b(a) | ((unsigned int)f2b(b) << 16);
}

#define GLOAD_LDS16(g, l) __builtin_amdgcn_global_load_lds( \
    (const __attribute__((address_space(1))) unsigned int*)(g), \
    (__attribute__((address_space(3))) unsigned int*)(l), 16, 0, 0)

// swizzled fragment read: row-major [128][128] bf16 tile, 16B slot ^= row&15
#define FRAG(buf, row, kt) (*(const short8*)&(buf)[(((row) << 7)) + \
    ((((((kt) << 2) + lk)) ^ ((row) & 15)) << 3)])

// ---------------- workspace layout (bytes) ----------------
#define OFF_XB     ((size_t)0)           // x bf16            [4096][2048]
#define OFF_WQKVB  ((size_t)16777216)    // w_qkv bf16        [6144][2048]
#define OFF_WGATEB ((size_t)41943040)    // w_gate bf16       [2048][2048]
#define OFF_WOUTB  ((size_t)50331648)    // w_out bf16        [2048][2048]
#define OFF_QB     ((size_t)58720256)    // q bf16            [BH][2048][128]
#define OFF_KB     ((size_t)75497472)    // k bf16            [BH][2048][128]
#define OFF_VTB    ((size_t)92274688)    // v^T bf16          [BH][16][128 d][128 j]
#define OFF_KVC    ((size_t)109051904)   // transposed states f32 [BH][16][128 d][128 e]
#define OFF_ATTN   ((size_t)142606336)   // attn out f32      [B][N][2048]
#define OFF_GATE   ((size_t)176160768)   // sigmoid gate bf16 [4096][2048]
#define OFF_YBUF   ((size_t)192937984)   // ybuf bf16 (late) / kT*lam bf16 (early)
#define WS_NEED    ((size_t)209715200)

// ---------------- fp32 -> bf16 cast ----------------
__global__ __launch_bounds__(256)
void cast_f2b(const float* __restrict__ in, unsigned short* __restrict__ o, int n)
{
  int idx = (blockIdx.x * 256 + threadIdx.x) * 4;
  if (idx >= n) return;
  float4 v = *(const float4*)&in[idx];
  ushort4 u;
  u.x = f2b(v.x); u.y = f2b(v.y); u.z = f2b(v.z); u.w = f2b(v.w);
  *(ushort4*)&o[idx] = u;
}

// ---------------- bf16 GEMM: C[M,N] = A[M,K] * B[N,K]^T ----------------
// EPI 0: f32 -> o0.  EPI 1: silu -> q(o0), k(o1), kT*lam(o3), vT(o2).
// EPI 2: sigmoid bf16 -> o0.
template<int EPI>
__global__ __launch_bounds__(256)
void gemm_bt(const unsigned short* __restrict__ A, const unsigned short* __restrict__ Bm,
             int K, int Nn, void* __restrict__ o0, void* __restrict__ o1,
             void* __restrict__ o2, void* __restrict__ o3,
             const float* __restrict__ slope)
{
  __shared__ unsigned short As[4096];
  __shared__ unsigned short Bs[4096];
  const int tid  = threadIdx.x;
  const int lane = tid & 63, w = tid >> 6;
  const int mBase = blockIdx.y << 7, nBase = blockIdx.x << 7;

  f32x4 zero = {0.f, 0.f, 0.f, 0.f};
  f32x4 acc[4][4];
#pragma unroll
  for (int m = 0; m < 4; ++m)
#pragma unroll
    for (int n = 0; n < 4; ++n) acc[m][n] = zero;

  const int wr = w >> 1, wc = w & 1;
  const int rA = (wr << 6) + (lane & 15);
  const int cB = (wc << 6) + (lane & 15);
  const int kg = (lane >> 4) << 3;
  const int segBase = w << 7;
  const int nIter = K >> 5;

  for (int kt = 0; kt < nIter; ++kt) {
    const int k0 = kt << 5;
#pragma unroll
    for (int rep = 0; rep < 2; ++rep) {
      int seg = segBase + (rep << 6) + lane;
      int r  = seg >> 2;
      int c8 = (seg & 3) << 3;
      GLOAD_LDS16(A  + ((size_t)(mBase + r) * K + k0 + c8), &As[(segBase + (rep << 6)) << 3]);
      GLOAD_LDS16(Bm + ((size_t)(nBase + r) * K + k0 + c8), &Bs[(segBase + (rep << 6)) << 3]);
    }
    __syncthreads();
    short8 af[4], bfv[4];
#pragma unroll
    for (int m = 0; m < 4; ++m) af[m]  = *(const short8*)&As[((rA + (m << 4)) << 5) + kg];
#pragma unroll
    for (int n = 0; n < 4; ++n) bfv[n] = *(const short8*)&Bs[((cB + (n << 4)) << 5) + kg];
#pragma unroll
    for (int m = 0; m < 4; ++m)
#pragma unroll
      for (int n = 0; n < 4; ++n)
        acc[m][n] = __builtin_amdgcn_mfma_f32_16x16x32_bf16(af[m], bfv[n], acc[m][n], 0, 0, 0);
    __syncthreads();
  }

#pragma unroll
  for (int m = 0; m < 4; ++m) {
#pragma unroll
    for (int n = 0; n < 4; ++n) {
      const int row0 = mBase + (wr << 6) + (m << 4) + ((lane >> 4) << 2);
      const int col  = nBase + (wc << 6) + (n << 4) + (lane & 15);
      f32x4 v = acc[m][n];
#pragma unroll
      for (int i2 = 0; i2 < 4; ++i2) {
        const int row = row0 + i2;
        float val = v[i2];
        if (EPI == 0) {
          ((float*)o0)[(size_t)row * Nn + col] = val;
        } else if (EPI == 1) {
          float sv = val / (1.f + __expf(-val));       // silu
          int hh = col / 384;
          int r3 = col - hh * 384;
          int which = r3 >> 7;
          int dd = r3 & 127;
          int bb = row >> 11, nn = row & 2047;
          int bh = bb * 16 + hh;
          unsigned short sb = f2b(sv);
          size_t toff = ((size_t)bh << 18) + ((size_t)(nn >> 7) << 14)
                      + ((size_t)dd << 7) + (size_t)(nn & 127);
          if (which == 0) {
            ((unsigned short*)o0)[(((size_t)bh << 11) + nn) * 128 + dd] = sb;
          } else if (which == 1) {
            ((unsigned short*)o1)[(((size_t)bh << 11) + nn) * 128 + dd] = sb;
            float lam = __expf(-slope[hh] * (float)(127 - (nn & 127)));
            ((unsigned short*)o3)[toff] = f2b(sv * lam);
          } else {
            ((unsigned short*)o2)[toff] = sb;
          }
        } else {
          float sg = 1.f / (1.f + __expf(-val));       // sigmoid
          ((unsigned short*)o0)[(size_t)row * Nn + col] = f2b(sg);
        }
      }
    }
  }
}

// ---------------- MFMA per-chunk local (transposed) KV ----------------
// T_c[d][e] = sum_j VT[d][j] * KTlam[e][j]   (lam^{127-j} pre-folded into KT)
__global__ __launch_bounds__(256, 2)
void chunk_kv_mfma(const unsigned short* __restrict__ vtg,
                   const unsigned short* __restrict__ ktg,
                   float* __restrict__ KVc)
{
  __shared__ unsigned short VTs[16384], KTs[16384];
  const int blk = blockIdx.x;                    // bh*16 + c
  const int tid = threadIdx.x, lane = tid & 63, w = tid >> 6;
  const int wr = w >> 1, wc = w & 1, lr = lane & 15, lk = lane >> 4;
  const size_t base = (size_t)blk << 14;
#pragma unroll
  for (int it = 0; it < 8; ++it) {
    int segw = (w << 3) + it;
    int sg = (segw << 6) + lane;
    int r = sg >> 4, sl = sg & 15;
    size_t goff = ((size_t)r << 7) + (size_t)((sl ^ (r & 15)) << 3);
    GLOAD_LDS16(vtg + base + goff, &VTs[segw << 9]);
    GLOAD_LDS16(ktg + base + goff, &KTs[segw << 9]);
  }
  __syncthreads();
  f32x4 zero = {0.f,0.f,0.f,0.f};
  f32x4 acc[4][4];
#pragma unroll
  for (int m = 0; m < 4; ++m)
#pragma unroll
    for (int n = 0; n < 4; ++n) acc[m][n] = zero;
#pragma unroll
  for (int kt = 0; kt < 4; ++kt) {
    short8 af[4], bf2[4];
#pragma unroll
    for (int m = 0; m < 4; ++m) af[m]  = FRAG(VTs, (wr << 6) + (m << 4) + lr, kt);
#pragma unroll
    for (int n = 0; n < 4; ++n) bf2[n] = FRAG(KTs, (wc << 6) + (n << 4) + lr, kt);
#pragma unroll
    for (int m = 0; m < 4; ++m)
#pragma unroll
      for (int n = 0; n < 4; ++n)
        acc[m][n] = __builtin_amdgcn_mfma_f32_16x16x32_bf16(af[m], bf2[n], acc[m][n], 0, 0, 0);
  }
  float* outp = KVc + base;
#pragma unroll
  for (int m = 0; m < 4; ++m)
#pragma unroll
    for (int n = 0; n < 4; ++n)
#pragma unroll
      for (int r2 = 0; r2 < 4; ++r2)
        outp[(size_t)((wr << 6) + (m << 4) + (lk << 2) + r2) * 128
             + (wc << 6) + (n << 4) + lr] = acc[m][n][r2];
}

// ---------------- sequential chunk combine (transposed states) ----------------
// KVc[c] <- T-state BEFORE chunk c; outkv written un-transposed.
__global__ __launch_bounds__(256)
void combine_kv(float* __restrict__ KVc, const float* __restrict__ past_kv,
                const float* __restrict__ slope, float* __restrict__ outkv)
{
  const int bh = blockIdx.x >> 3, slice = blockIdx.x & 7;
  const int h = bh & 15;
  const int tid = threadIdx.x;
  const float lamC = __expf(-slope[h] * 128.f);
  const int f0 = (slice << 11) + tid;
  float S[8];
  const float* pp = past_kv + ((size_t)bh << 14);
#pragma unroll
  for (int i = 0; i < 8; ++i) {
    int f = f0 + (i << 8);
    int d = f >> 7, e = f & 127;
    S[i] = pp[(e << 7) + d];                   // transpose on read
  }
  for (int cc = 0; cc < 16; ++cc) {
    float* p = KVc + ((((size_t)bh << 4) + cc) << 14);
#pragma unroll
    for (int i = 0; i < 8; ++i) {
      int f = f0 + (i << 8);
      float t = p[f];
      p[f] = S[i];
      S[i] = lamC * S[i] + t;
    }
  }
  float* op = outkv + ((size_t)bh << 14);
#pragma unroll
  for (int i = 0; i < 8; ++i) {
    int f = f0 + (i << 8);
    int d = f >> 7, e = f & 127;
    op[(e << 7) + d] = S[i];                   // transpose on write
  }
}

// ---------------- MFMA per-chunk outputs ----------------
// O[i][d] = lam^{i+1} (Q @ S)[i][d] + (mask(QK^T) @ V)[i][d]
__global__ __launch_bounds__(256, 1)
void chunk_out_mfma(const unsigned short* __restrict__ qg,
                    const unsigned short* __restrict__ kg,
                    const unsigned short* __restrict__ vtg,
                    const float* __restrict__ States,
                    const float* __restrict__ slope,
                    float* __restrict__ attn)
{
  __shared__ unsigned short Qs[16384], Ks[16384], VTs[16384], STs[16384];
  const int blk = blockIdx.x;
  const int cc = blk & 15, h = (blk >> 4) & 15, b = blk >> 8;
  const int tid = threadIdx.x, lane = tid & 63, w = tid >> 6;
  const int wr = w >> 1, wc = w & 1, lr = lane & 15, lk = lane >> 4;
  const size_t base = (size_t)blk << 14;     // q/k chunk AND vT/state chunk offset
  const float s = slope[h];

#pragma unroll
  for (int it = 0; it < 8; ++it) {
    int segw = (w << 3) + it;
    int sg = (segw << 6) + lane;
    int r = sg >> 4, sl = sg & 15;
    size_t goff = ((size_t)r << 7) + (size_t)((sl ^ (r & 15)) << 3);
    GLOAD_LDS16(qg  + base + goff, &Qs[segw << 9]);
    GLOAD_LDS16(kg  + base + goff, &Ks[segw << 9]);
    GLOAD_LDS16(vtg + base + goff, &VTs[segw << 9]);
  }
  const float* Sg = States + base;
#pragma unroll
  for (int it = 0; it < 8; ++it) {
    int idx = ((it << 8) + tid) << 3;
    float4 a0 = *(const float4*)&Sg[idx];
    float4 a1 = *(const float4*)&Sg[idx + 4];
    int r = idx >> 7, c = idx & 127;
    int sl = (c >> 3) ^ (r & 15);
    uint4 u = make_uint4(pk2(a0.x,a0.y), pk2(a0.z,a0.w), pk2(a1.x,a1.y), pk2(a1.z,a1.w));
    *(uint4*)&STs[(r << 7) + (sl << 3)] = u;
  }
  __syncthreads();

  f32x4 zero = {0.f,0.f,0.f,0.f};
  f32x4 Oa[4][4], Pa[4][4];
#pragma unroll
  for (int m = 0; m < 4; ++m)
#pragma unroll
    for (int n = 0; n < 4; ++n) { Oa[m][n] = zero; Pa[m][n] = zero; }

  // fused: O += Q@ST (k=e), P += Q@K^T (k=e) — Q frags shared
#pragma unroll
  for (int kt = 0; kt < 4; ++kt) {
    short8 qf[4], bst[4], bk[4];
#pragma unroll
    for (int m = 0; m < 4; ++m) qf[m] = FRAG(Qs, (wr << 6) + (m << 4) + lr, kt);
#pragma unroll
    for (int n = 0; n < 4; ++n) {
      int cn = (wc << 6) + (n << 4) + lr;
      bst[n] = FRAG(STs, cn, kt);
      bk[n]  = FRAG(Ks,  cn, kt);
    }
#pragma unroll
    for (int m = 0; m < 4; ++m)
#pragma unroll
      for (int n = 0; n < 4; ++n) {
        Oa[m][n] = __builtin_amdgcn_mfma_f32_16x16x32_bf16(qf[m], bst[n], Oa[m][n], 0, 0, 0);
        Pa[m][n] = __builtin_amdgcn_mfma_f32_16x16x32_bf16(qf[m], bk[n],  Pa[m][n], 0, 0, 0);
      }
  }

  // decay factors: lam^{i-j} = e^{-s i} * e^{s j}; O scale lam^{i+1}
  float emi[16];
#pragma unroll
  for (int m = 0; m < 4; ++m)
#pragma unroll
    for (int r2 = 0; r2 < 4; ++r2)
      emi[(m << 2) + r2] = __expf(-s * (float)((wr << 6) + (m << 4) + (lk << 2) + r2));
  const float lam1 = __expf(-s);
  float epj[4];
#pragma unroll
  for (int n = 0; n < 4; ++n)
    epj[n] = __expf(s * (float)((wc << 6) + (n << 4) + lr));

#pragma unroll
  for (int m = 0; m < 4; ++m)
#pragma unroll
    for (int n = 0; n < 4; ++n) {
      const int j = (wc << 6) + (n << 4) + lr;
#pragma unroll
      for (int r2 = 0; r2 < 4; ++r2) {
        const int i = (wr << 6) + (m << 4) + (lk << 2) + r2;
        Oa[m][n][r2] *= emi[(m << 2) + r2] * lam1;
        float pv = Pa[m][n][r2] * emi[(m << 2) + r2] * epj[n];
        Pa[m][n][r2] = (i >= j) ? pv : 0.f;
      }
    }
  __syncthreads();            // all waves done reading K

  // write masked P (bf16, swizzled) into Ks
#pragma unroll
  for (int m = 0; m < 4; ++m)
#pragma unroll
    for (int n = 0; n < 4; ++n) {
      const int j = (wc << 6) + (n << 4) + lr;
#pragma unroll
      for (int r2 = 0; r2 < 4; ++r2) {
        const int i = (wr << 6) + (m << 4) + (lk << 2) + r2;
        const int sl = (j >> 3) ^ (i & 15);
        Ks[(i << 7) + (sl << 3) + (j & 7)] = f2b(Pa[m][n][r2]);
      }
    }
  __syncthreads();

  // O += P @ V  (k=j): A = P rows, B = VT rows
#pragma unroll
  for (int kt = 0; kt < 4; ++kt) {
    short8 pf[4], vf[4];
#pragma unroll
    for (int m = 0; m < 4; ++m) pf[m] = FRAG(Ks,  (wr << 6) + (m << 4) + lr, kt);
#pragma unroll
    for (int n = 0; n < 4; ++n) vf[n] = FRAG(VTs, (wc << 6) + (n << 4) + lr, kt);
#pragma unroll
    for (int m = 0; m < 4; ++m)
#pragma unroll
      for (int n = 0; n < 4; ++n)
        Oa[m][n] = __builtin_amdgcn_mfma_f32_16x16x32_bf16(pf[m], vf[n], Oa[m][n], 0, 0, 0);
  }

#pragma unroll
  for (int m = 0; m < 4; ++m)
#pragma unroll
    for (int n = 0; n < 4; ++n) {
      const int c = (wc << 6) + (n << 4) + lr;
#pragma unroll
      for (int r2 = 0; r2 < 4; ++r2) {
        const int i = (wr << 6) + (m << 4) + (lk << 2) + r2;
        attn[(((size_t)((b << 11) + (cc << 7) + i)) << 11) + (h << 7) + c] = Oa[m][n][r2];
      }
    }
}

// ---------------- RMSNorm * norm_w * sigmoid-gate -> bf16 ----------------
__global__ __launch_bounds__(256)
void norm_gate(const float* __restrict__ attn, const unsigned short* __restrict__ gateb,
               const float* __restrict__ normw, unsigned short* __restrict__ ybuf)
{
  const int row = blockIdx.x;
  const int tid = threadIdx.x;
  const float* ar = attn + ((size_t)row << 11);
  float4 v0 = *(const float4*)&ar[tid * 8];
  float4 v1 = *(const float4*)&ar[tid * 8 + 4];
  float ss = v0.x*v0.x + v0.y*v0.y + v0.z*v0.z + v0.w*v0.w
           + v1.x*v1.x + v1.y*v1.y + v1.z*v1.z + v1.w*v1.w;
#pragma unroll
  for (int off = 32; off > 0; off >>= 1) ss += __shfl_down(ss, off);
  __shared__ float red[4];
  if ((tid & 63) == 0) red[tid >> 6] = ss;
  __syncthreads();
  float tot = red[0] + red[1] + red[2] + red[3];
  float scale = rsqrtf(tot * (1.f / 2048.f) + 1e-6f);
  uint4 gg = *(const uint4*)&gateb[((size_t)row << 11) + tid * 8];
  float4 w0 = *(const float4*)&normw[tid * 8];
  float4 w1 = *(const float4*)&normw[tid * 8 + 4];
  ushort4 o0, o1;
  o0.x = f2b(v0.x * scale * w0.x * blo(gg.x));
  o0.y = f2b(v0.y * scale * w0.y * bhi(gg.x));
  o0.z = f2b(v0.z * scale * w0.z * blo(gg.y));
  o0.w = f2b(v0.w * scale * w0.w * bhi(gg.y));
  o1.x = f2b(v1.x * scale * w1.x * blo(gg.z));
  o1.y = f2b(v1.y * scale * w1.y * bhi(gg.z));
  o1.z = f2b(v1.z * scale * w1.z * blo(gg.w));
  o1.w = f2b(v1.w * scale * w1.w * bhi(gg.w));
  *(ushort4*)&ybuf[((size_t)row << 11) + tid * 8]     = o0;
  *(ushort4*)&ybuf[((size_t)row << 11) + tid * 8 + 4] = o1;
}

// ---------------------------------------------------------------------------
extern "C" void kernel_launch(void* const* d_in, const int* in_sizes, int n_in,
                              void* d_out, int out_size, void* d_ws, size_t ws_size,
                              hipStream_t stream)
{
  const float* x       = (const float*)d_in[0];
  const float* past_kv = (const float*)d_in[1];
  const float* slope   = (const float*)d_in[2];
  const float* w_qkv   = (const float*)d_in[3];
  const float* w_gate  = (const float*)d_in[4];
  const float* w_out   = (const float*)d_in[5];
  const float* norm_w  = (const float*)d_in[6];
  float* out    = (float*)d_out;
  float* out_kv = out + 8388608;
  if (ws_size < WS_NEED) return;
  char* ws = (char*)d_ws;
  unsigned short* xb     = (unsigned short*)(ws + OFF_XB);
  unsigned short* wqkvb  = (unsigned short*)(ws + OFF_WQKVB);
  unsigned short* wgateb = (unsigned short*)(ws + OFF_WGATEB);
  unsigned short* woutb  = (unsigned short*)(ws + OFF_WOUTB);
  unsigned short* qb     = (unsigned short*)(ws + OFF_QB);
  unsigned short* kb     = (unsigned short*)(ws + OFF_KB);
  unsigned short* vtb    = (unsigned short*)(ws + OFF_VTB);
  unsigned short* ktb    = (unsigned short*)(ws + OFF_YBUF);  // aliased (early lifetime)
  float*          kvc    = (float*)(ws + OFF_KVC);
  float*          attn   = (float*)(ws + OFF_ATTN);
  unsigned short* gate   = (unsigned short*)(ws + OFF_GATE);
  unsigned short* ybuf   = (unsigned short*)(ws + OFF_YBUF);  // late lifetime

  cast_f2b<<<8192,  256, 0, stream>>>(x,      xb,     8388608);
  cast_f2b<<<12288, 256, 0, stream>>>(w_qkv,  wqkvb,  12582912);
  cast_f2b<<<4096,  256, 0, stream>>>(w_gate, wgateb, 4194304);
  cast_f2b<<<4096,  256, 0, stream>>>(w_out,  woutb,  4194304);

  gemm_bt<1><<<dim3(48, 32), 256, 0, stream>>>(xb, wqkvb, 2048, 6144,
                                               qb, kb, vtb, ktb, slope);
  gemm_bt<2><<<dim3(16, 32), 256, 0, stream>>>(xb, wgateb, 2048, 2048,
                                               gate, nullptr, nullptr, nullptr, nullptr);

  chunk_kv_mfma<<<512, 256, 0, stream>>>(vtb, ktb, kvc);
  combine_kv   <<<256, 256, 0, stream>>>(kvc, past_kv, slope, out_kv);
  chunk_out_mfma<<<512, 256, 0, stream>>>(qb, kb, vtb, kvc, slope, attn);

  norm_gate<<<4096, 256, 0, stream>>>(attn, gate, norm_w, ybuf);
  gemm_bt<0><<<dim3(16, 32), 256, 0, stream>>>(ybuf, woutb, 2048, 2048,
                                               out, nullptr, nullptr, nullptr, nullptr);
}

// Round 3
// 472.341 us; speedup vs baseline: 2.0335x; 1.0997x over previous
//
#include <hip/hip_runtime.h>

// ---------------------------------------------------------------------------
// MiniMax Lightning Attention (B=2,N=2048,D=2048,H=16,HD=128), fp32 in/out.
// cast->bf16 | fused GEMM qkv+gate (silu/sigmoid, LDS-transposed kT/vT) |
// MFMA chunk_kv | combine | MFMA chunk_out | norm*gate | GEMM out.
// ---------------------------------------------------------------------------

typedef __attribute__((ext_vector_type(8))) short short8;
typedef __attribute__((ext_vector_type(4))) float f32x4;

__device__ __forceinline__ float blo(unsigned int u){ return __uint_as_float(u << 16); }
__device__ __forceinline__ float bhi(unsigned int u){ return __uint_as_float(u & 0xffff0000u); }
__device__ __forceinline__ unsigned short f2b(float f){
  unsigned int u = __float_as_uint(f);
  return (unsigned short)((u + 0x7fffu + ((u >> 16) & 1u)) >> 16);
}
__device__ __forceinline__ unsigned int pk2(float a, float b){
  return (unsigned int)f2b(a) | ((unsigned int)f2b(b) << 16);
}

#define GLOAD_LDS16(g, l) __builtin_amdgcn_global_load_lds( \
    (const __attribute__((address_space(1))) unsigned int*)(g), \
    (__attribute__((address_space(3))) unsigned int*)(l), 16, 0, 0)

// swizzled fragment read: row-major [128][128] bf16 tile, 16B slot ^= row&15
#define FRAG(buf, row, kt) (*(const short8*)&(buf)[(((row) << 7)) + \
    ((((((kt) << 2) + lk)) ^ ((row) & 15)) << 3)])

// ---------------- workspace layout (bytes) ----------------
#define OFF_XB     ((size_t)0)           // x bf16            [4096][2048]
#define OFF_WQKVB  ((size_t)16777216)    // w_qkv bf16        [6144][2048]
#define OFF_WGATEB ((size_t)41943040)    // w_gate bf16       [2048][2048] (contiguous after wqkv)
#define OFF_WOUTB  ((size_t)50331648)    // w_out bf16        [2048][2048]
#define OFF_QB     ((size_t)58720256)    // q bf16            [BH][2048][128]
#define OFF_KB     ((size_t)75497472)    // k bf16            [BH][2048][128]
#define OFF_VTB    ((size_t)92274688)    // v^T bf16          [BH][16][128 d][128 j]
#define OFF_KVC    ((size_t)109051904)   // transposed states f32 [BH][16][128 d][128 e]
#define OFF_ATTN   ((size_t)142606336)   // attn out f32      [B][N][2048]
#define OFF_GATE   ((size_t)176160768)   // sigmoid gate bf16 [4096][2048]
#define OFF_YBUF   ((size_t)192937984)   // ybuf bf16 (late) / kT*lam bf16 (early)
#define WS_NEED    ((size_t)209715200)

// ---------------- fp32 -> bf16 cast ----------------
__global__ __launch_bounds__(256)
void cast_f2b(const float* __restrict__ in, unsigned short* __restrict__ o, int n)
{
  int idx = (blockIdx.x * 256 + threadIdx.x) * 4;
  if (idx >= n) return;
  float4 v = *(const float4*)&in[idx];
  ushort4 u;
  u.x = f2b(v.x); u.y = f2b(v.y); u.z = f2b(v.z); u.w = f2b(v.w);
  *(ushort4*)&o[idx] = u;
}

// ---------------- bf16 GEMM: C[M,N] = A[M,K] * B[N,K]^T ----------------
// EPI 0: f32 -> o0 (ld=Nn).
// EPI 1: fused qkv+gate epilogue. Per-block uniform region:
//        which 0: silu -> q(o0) row-major
//        which 1: silu -> k(o1) row-major + kT*lam(o3) via LDS transpose
//        which 2: silu -> vT(o2) via LDS transpose
//        which 3: sigmoid -> gate(o4) row-major
template<int EPI>
__global__ __launch_bounds__(256)
void gemm_bt(const unsigned short* __restrict__ A, const unsigned short* __restrict__ Bm,
             int K, int Nn, void* __restrict__ o0, void* __restrict__ o1,
             void* __restrict__ o2, void* __restrict__ o3, void* __restrict__ o4,
             const float* __restrict__ slope)
{
  __shared__ unsigned short S[(EPI == 1) ? 16384 : 8192];
  unsigned short* Asp = S;
  unsigned short* Bsp = S + 4096;
  const int tid  = threadIdx.x;
  const int lane = tid & 63, w = tid >> 6;
  const int mBase = blockIdx.y << 7, nBase = blockIdx.x << 7;

  f32x4 zero = {0.f, 0.f, 0.f, 0.f};
  f32x4 acc[4][4];
#pragma unroll
  for (int m = 0; m < 4; ++m)
#pragma unroll
    for (int n = 0; n < 4; ++n) acc[m][n] = zero;

  const int wr = w >> 1, wc = w & 1;
  const int rA = (wr << 6) + (lane & 15);
  const int cB = (wc << 6) + (lane & 15);
  const int kg = (lane >> 4) << 3;
  const int segBase = w << 7;
  const int nIter = K >> 5;

  for (int kt = 0; kt < nIter; ++kt) {
    const int k0 = kt << 5;
#pragma unroll
    for (int rep = 0; rep < 2; ++rep) {
      int seg = segBase + (rep << 6) + lane;
      int r  = seg >> 2;
      int c8 = (seg & 3) << 3;
      GLOAD_LDS16(A  + ((size_t)(mBase + r) * K + k0 + c8), &Asp[(segBase + (rep << 6)) << 3]);
      GLOAD_LDS16(Bm + ((size_t)(nBase + r) * K + k0 + c8), &Bsp[(segBase + (rep << 6)) << 3]);
    }
    __syncthreads();
    short8 af[4], bfv[4];
#pragma unroll
    for (int m = 0; m < 4; ++m) af[m]  = *(const short8*)&Asp[((rA + (m << 4)) << 5) + kg];
#pragma unroll
    for (int n = 0; n < 4; ++n) bfv[n] = *(const short8*)&Bsp[((cB + (n << 4)) << 5) + kg];
#pragma unroll
    for (int m = 0; m < 4; ++m)
#pragma unroll
      for (int n = 0; n < 4; ++n)
        acc[m][n] = __builtin_amdgcn_mfma_f32_16x16x32_bf16(af[m], bfv[n], acc[m][n], 0, 0, 0);
    __syncthreads();
  }

  // epilogue: C/D layout col = lane&15, row = (lane>>4)*4 + reg  [m89-verified]
  const int lk4 = (lane >> 4) << 2;
  if (EPI == 0) {
#pragma unroll
    for (int m = 0; m < 4; ++m)
#pragma unroll
      for (int n = 0; n < 4; ++n) {
        const int row0 = mBase + (wr << 6) + (m << 4) + lk4;
        const int col  = nBase + (wc << 6) + (n << 4) + (lane & 15);
        f32x4 v = acc[m][n];
#pragma unroll
        for (int r2 = 0; r2 < 4; ++r2)
          ((float*)o0)[(size_t)(row0 + r2) * Nn + col] = v[r2];
      }
  } else {
    // ---- block-uniform region classification ----
    const int bb = mBase >> 11, cc = (mBase & 2047) >> 7;
    int which, hh = 0;
    if (nBase >= 6144) { which = 3; }
    else { hh = nBase / 384; which = (nBase - hh * 384) >> 7; }
    const int bh = (bb << 4) + hh;

#pragma unroll
    for (int m = 0; m < 4; ++m) {
#pragma unroll
      for (int n = 0; n < 4; ++n) {
        const int lrow = (wr << 6) + (m << 4) + lk4;        // local row (mult of 4)
        const int dloc = (wc << 6) + (n << 4) + (lane & 15); // local col
        f32x4 v = acc[m][n];
        if (which == 3) {
#pragma unroll
          for (int r2 = 0; r2 < 4; ++r2) {
            float sg = 1.f / (1.f + __expf(-v[r2]));
            ((unsigned short*)o4)[((size_t)(mBase + lrow + r2) << 11)
                                  + (nBase - 6144) + dloc] = f2b(sg);
          }
        } else {
          float sv[4];
#pragma unroll
          for (int r2 = 0; r2 < 4; ++r2) sv[r2] = v[r2] / (1.f + __expf(-v[r2]));
          if (which <= 1) {
            unsigned short* dst = (which == 0) ? (unsigned short*)o0 : (unsigned short*)o1;
#pragma unroll
            for (int r2 = 0; r2 < 4; ++r2) {
              int nn = (mBase & 2047) + lrow + r2;
              dst[(((size_t)bh << 11) + nn) * 128 + dloc] = f2b(sv[r2]);
            }
          }
          if (which >= 1) {   // transpose staging for kT / vT
            int sidx = (dloc << 7) + ((((lrow >> 2) ^ (dloc & 31))) << 2);
            *(unsigned int*)&S[sidx]     = pk2(sv[0], sv[1]);
            *(unsigned int*)&S[sidx + 2] = pk2(sv[2], sv[3]);
          }
        }
      }
    }
    if (which == 1 || which == 2) {
      __syncthreads();
      const int nnc = tid & 15, dd0 = (tid >> 4) << 3;
      const int nn0 = nnc << 3;
      const size_t baseT = ((size_t)((bh << 4) + cc) << 14);
      float lamf[8];
      if (which == 1) {
        const float s = slope[hh];
#pragma unroll
        for (int t = 0; t < 8; ++t) lamf[t] = __expf(-s * (float)(127 - (nn0 + t)));
      }
#pragma unroll
      for (int i = 0; i < 8; ++i) {
        const int dd = dd0 + i;
        const int s0 = (((nnc << 1)     ) ^ (dd & 31)) << 2;
        const int s1 = (((nnc << 1) | 1 ) ^ (dd & 31)) << 2;
        uint2 a  = *(const uint2*)&S[(dd << 7) + s0];
        uint2 b2 = *(const uint2*)&S[(dd << 7) + s1];
        if (which == 1) {
          a.x  = pk2(blo(a.x)  * lamf[0], bhi(a.x)  * lamf[1]);
          a.y  = pk2(blo(a.y)  * lamf[2], bhi(a.y)  * lamf[3]);
          b2.x = pk2(blo(b2.x) * lamf[4], bhi(b2.x) * lamf[5]);
          b2.y = pk2(blo(b2.y) * lamf[6], bhi(b2.y) * lamf[7]);
          *(uint4*)((unsigned short*)o3 + baseT + ((size_t)dd << 7) + nn0)
              = make_uint4(a.x, a.y, b2.x, b2.y);
        } else {
          *(uint4*)((unsigned short*)o2 + baseT + ((size_t)dd << 7) + nn0)
              = make_uint4(a.x, a.y, b2.x, b2.y);
        }
      }
    }
  }
}

// ---------------- MFMA per-chunk local (transposed) KV ----------------
// T_c[d][e] = sum_j VT[d][j] * KTlam[e][j]   (lam^{127-j} pre-folded into KT)
__global__ __launch_bounds__(256, 2)
void chunk_kv_mfma(const unsigned short* __restrict__ vtg,
                   const unsigned short* __restrict__ ktg,
                   float* __restrict__ KVc)
{
  __shared__ unsigned short VTs[16384], KTs[16384];
  const int blk = blockIdx.x;                    // bh*16 + c
  const int tid = threadIdx.x, lane = tid & 63, w = tid >> 6;
  const int wr = w >> 1, wc = w & 1, lr = lane & 15, lk = lane >> 4;
  const size_t base = (size_t)blk << 14;
#pragma unroll
  for (int it = 0; it < 8; ++it) {
    int segw = (w << 3) + it;
    int sg = (segw << 6) + lane;
    int r = sg >> 4, sl = sg & 15;
    size_t goff = ((size_t)r << 7) + (size_t)((sl ^ (r & 15)) << 3);
    GLOAD_LDS16(vtg + base + goff, &VTs[segw << 9]);
    GLOAD_LDS16(ktg + base + goff, &KTs[segw << 9]);
  }
  __syncthreads();
  f32x4 zero = {0.f,0.f,0.f,0.f};
  f32x4 acc[4][4];
#pragma unroll
  for (int m = 0; m < 4; ++m)
#pragma unroll
    for (int n = 0; n < 4; ++n) acc[m][n] = zero;
#pragma unroll
  for (int kt = 0; kt < 4; ++kt) {
    short8 af[4], bf2[4];
#pragma unroll
    for (int m = 0; m < 4; ++m) af[m]  = FRAG(VTs, (wr << 6) + (m << 4) + lr, kt);
#pragma unroll
    for (int n = 0; n < 4; ++n) bf2[n] = FRAG(KTs, (wc << 6) + (n << 4) + lr, kt);
#pragma unroll
    for (int m = 0; m < 4; ++m)
#pragma unroll
      for (int n = 0; n < 4; ++n)
        acc[m][n] = __builtin_amdgcn_mfma_f32_16x16x32_bf16(af[m], bf2[n], acc[m][n], 0, 0, 0);
  }
  float* outp = KVc + base;
#pragma unroll
  for (int m = 0; m < 4; ++m)
#pragma unroll
    for (int n = 0; n < 4; ++n)
#pragma unroll
      for (int r2 = 0; r2 < 4; ++r2)
        outp[(size_t)((wr << 6) + (m << 4) + (lk << 2) + r2) * 128
             + (wc << 6) + (n << 4) + lr] = acc[m][n][r2];
}

// ---------------- sequential chunk combine (transposed states) ----------------
__global__ __launch_bounds__(256)
void combine_kv(float* __restrict__ KVc, const float* __restrict__ past_kv,
                const float* __restrict__ slope, float* __restrict__ outkv)
{
  const int bh = blockIdx.x >> 3, slice = blockIdx.x & 7;
  const int h = bh & 15;
  const int tid = threadIdx.x;
  const float lamC = __expf(-slope[h] * 128.f);
  const int f0 = (slice << 11) + tid;
  float S[8];
  const float* pp = past_kv + ((size_t)bh << 14);
#pragma unroll
  for (int i = 0; i < 8; ++i) {
    int f = f0 + (i << 8);
    int d = f >> 7, e = f & 127;
    S[i] = pp[(e << 7) + d];                   // transpose on read
  }
  for (int cc = 0; cc < 16; ++cc) {
    float* p = KVc + ((((size_t)bh << 4) + cc) << 14);
#pragma unroll
    for (int i = 0; i < 8; ++i) {
      int f = f0 + (i << 8);
      float t = p[f];
      p[f] = S[i];
      S[i] = lamC * S[i] + t;
    }
  }
  float* op = outkv + ((size_t)bh << 14);
#pragma unroll
  for (int i = 0; i < 8; ++i) {
    int f = f0 + (i << 8);
    int d = f >> 7, e = f & 127;
    op[(e << 7) + d] = S[i];                   // transpose on write
  }
}

// ---------------- MFMA per-chunk outputs ----------------
// O[i][d] = lam^{i+1} (Q @ S)[i][d] + (mask(QK^T) @ V)[i][d]
__global__ __launch_bounds__(256, 1)
void chunk_out_mfma(const unsigned short* __restrict__ qg,
                    const unsigned short* __restrict__ kg,
                    const unsigned short* __restrict__ vtg,
                    const float* __restrict__ States,
                    const float* __restrict__ slope,
                    float* __restrict__ attn)
{
  __shared__ unsigned short Qs[16384], Ks[16384], VTs[16384], STs[16384];
  const int blk = blockIdx.x;
  const int cc = blk & 15, h = (blk >> 4) & 15, b = blk >> 8;
  const int tid = threadIdx.x, lane = tid & 63, w = tid >> 6;
  const int wr = w >> 1, wc = w & 1, lr = lane & 15, lk = lane >> 4;
  const size_t base = (size_t)blk << 14;
  const float s = slope[h];

#pragma unroll
  for (int it = 0; it < 8; ++it) {
    int segw = (w << 3) + it;
    int sg = (segw << 6) + lane;
    int r = sg >> 4, sl = sg & 15;
    size_t goff = ((size_t)r << 7) + (size_t)((sl ^ (r & 15)) << 3);
    GLOAD_LDS16(qg  + base + goff, &Qs[segw << 9]);
    GLOAD_LDS16(kg  + base + goff, &Ks[segw << 9]);
    GLOAD_LDS16(vtg + base + goff, &VTs[segw << 9]);
  }
  const float* Sg = States + base;
#pragma unroll
  for (int it = 0; it < 8; ++it) {
    int idx = ((it << 8) + tid) << 3;
    float4 a0 = *(const float4*)&Sg[idx];
    float4 a1 = *(const float4*)&Sg[idx + 4];
    int r = idx >> 7, c = idx & 127;
    int sl = (c >> 3) ^ (r & 15);
    uint4 u = make_uint4(pk2(a0.x,a0.y), pk2(a0.z,a0.w), pk2(a1.x,a1.y), pk2(a1.z,a1.w));
    *(uint4*)&STs[(r << 7) + (sl << 3)] = u;
  }
  __syncthreads();

  f32x4 zero = {0.f,0.f,0.f,0.f};
  f32x4 Oa[4][4], Pa[4][4];
#pragma unroll
  for (int m = 0; m < 4; ++m)
#pragma unroll
    for (int n = 0; n < 4; ++n) { Oa[m][n] = zero; Pa[m][n] = zero; }

#pragma unroll
  for (int kt = 0; kt < 4; ++kt) {
    short8 qf[4], bst[4], bk[4];
#pragma unroll
    for (int m = 0; m < 4; ++m) qf[m] = FRAG(Qs, (wr << 6) + (m << 4) + lr, kt);
#pragma unroll
    for (int n = 0; n < 4; ++n) {
      int cn = (wc << 6) + (n << 4) + lr;
      bst[n] = FRAG(STs, cn, kt);
      bk[n]  = FRAG(Ks,  cn, kt);
    }
#pragma unroll
    for (int m = 0; m < 4; ++m)
#pragma unroll
      for (int n = 0; n < 4; ++n) {
        Oa[m][n] = __builtin_amdgcn_mfma_f32_16x16x32_bf16(qf[m], bst[n], Oa[m][n], 0, 0, 0);
        Pa[m][n] = __builtin_amdgcn_mfma_f32_16x16x32_bf16(qf[m], bk[n],  Pa[m][n], 0, 0, 0);
      }
  }

  float emi[16];
#pragma unroll
  for (int m = 0; m < 4; ++m)
#pragma unroll
    for (int r2 = 0; r2 < 4; ++r2)
      emi[(m << 2) + r2] = __expf(-s * (float)((wr << 6) + (m << 4) + (lk << 2) + r2));
  const float lam1 = __expf(-s);
  float epj[4];
#pragma unroll
  for (int n = 0; n < 4; ++n)
    epj[n] = __expf(s * (float)((wc << 6) + (n << 4) + lr));

#pragma unroll
  for (int m = 0; m < 4; ++m)
#pragma unroll
    for (int n = 0; n < 4; ++n) {
      const int j = (wc << 6) + (n << 4) + lr;
#pragma unroll
      for (int r2 = 0; r2 < 4; ++r2) {
        const int i = (wr << 6) + (m << 4) + (lk << 2) + r2;
        Oa[m][n][r2] *= emi[(m << 2) + r2] * lam1;
        float pv = Pa[m][n][r2] * emi[(m << 2) + r2] * epj[n];
        Pa[m][n][r2] = (i >= j) ? pv : 0.f;
      }
    }
  __syncthreads();

#pragma unroll
  for (int m = 0; m < 4; ++m)
#pragma unroll
    for (int n = 0; n < 4; ++n) {
      const int j = (wc << 6) + (n << 4) + lr;
#pragma unroll
      for (int r2 = 0; r2 < 4; ++r2) {
        const int i = (wr << 6) + (m << 4) + (lk << 2) + r2;
        const int sl = (j >> 3) ^ (i & 15);
        Ks[(i << 7) + (sl << 3) + (j & 7)] = f2b(Pa[m][n][r2]);
      }
    }
  __syncthreads();

#pragma unroll
  for (int kt = 0; kt < 4; ++kt) {
    short8 pf[4], vf[4];
#pragma unroll
    for (int m = 0; m < 4; ++m) pf[m] = FRAG(Ks,  (wr << 6) + (m << 4) + lr, kt);
#pragma unroll
    for (int n = 0; n < 4; ++n) vf[n] = FRAG(VTs, (wc << 6) + (n << 4) + lr, kt);
#pragma unroll
    for (int m = 0; m < 4; ++m)
#pragma unroll
      for (int n = 0; n < 4; ++n)
        Oa[m][n] = __builtin_amdgcn_mfma_f32_16x16x32_bf16(pf[m], vf[n], Oa[m][n], 0, 0, 0);
  }

#pragma unroll
  for (int m = 0; m < 4; ++m)
#pragma unroll
    for (int n = 0; n < 4; ++n) {
      const int c = (wc << 6) + (n << 4) + lr;
#pragma unroll
      for (int r2 = 0; r2 < 4; ++r2) {
        const int i = (wr << 6) + (m << 4) + (lk << 2) + r2;
        attn[(((size_t)((b << 11) + (cc << 7) + i)) << 11) + (h << 7) + c] = Oa[m][n][r2];
      }
    }
}

// ---------------- RMSNorm * norm_w * sigmoid-gate -> bf16 ----------------
__global__ __launch_bounds__(256)
void norm_gate(const float* __restrict__ attn, const unsigned short* __restrict__ gateb,
               const float* __restrict__ normw, unsigned short* __restrict__ ybuf)
{
  const int row = blockIdx.x;
  const int tid = threadIdx.x;
  const float* ar = attn + ((size_t)row << 11);
  float4 v0 = *(const float4*)&ar[tid * 8];
  float4 v1 = *(const float4*)&ar[tid * 8 + 4];
  float ss = v0.x*v0.x + v0.y*v0.y + v0.z*v0.z + v0.w*v0.w
           + v1.x*v1.x + v1.y*v1.y + v1.z*v1.z + v1.w*v1.w;
#pragma unroll
  for (int off = 32; off > 0; off >>= 1) ss += __shfl_down(ss, off);
  __shared__ float red[4];
  if ((tid & 63) == 0) red[tid >> 6] = ss;
  __syncthreads();
  float tot = red[0] + red[1] + red[2] + red[3];
  float scale = rsqrtf(tot * (1.f / 2048.f) + 1e-6f);
  uint4 gg = *(const uint4*)&gateb[((size_t)row << 11) + tid * 8];
  float4 w0 = *(const float4*)&normw[tid * 8];
  float4 w1 = *(const float4*)&normw[tid * 8 + 4];
  ushort4 o0, o1;
  o0.x = f2b(v0.x * scale * w0.x * blo(gg.x));
  o0.y = f2b(v0.y * scale * w0.y * bhi(gg.x));
  o0.z = f2b(v0.z * scale * w0.z * blo(gg.y));
  o0.w = f2b(v0.w * scale * w0.w * bhi(gg.y));
  o1.x = f2b(v1.x * scale * w1.x * blo(gg.z));
  o1.y = f2b(v1.y * scale * w1.y * bhi(gg.z));
  o1.z = f2b(v1.z * scale * w1.z * blo(gg.w));
  o1.w = f2b(v1.w * scale * w1.w * bhi(gg.w));
  *(ushort4*)&ybuf[((size_t)row << 11) + tid * 8]     = o0;
  *(ushort4*)&ybuf[((size_t)row << 11) + tid * 8 + 4] = o1;
}

// ---------------------------------------------------------------------------
extern "C" void kernel_launch(void* const* d_in, const int* in_sizes, int n_in,
                              void* d_out, int out_size, void* d_ws, size_t ws_size,
                              hipStream_t stream)
{
  const float* x       = (const float*)d_in[0];
  const float* past_kv = (const float*)d_in[1];
  const float* slope   = (const float*)d_in[2];
  const float* w_qkv   = (const float*)d_in[3];
  const float* w_gate  = (const float*)d_in[4];
  const float* w_out   = (const float*)d_in[5];
  const float* norm_w  = (const float*)d_in[6];
  float* out    = (float*)d_out;
  float* out_kv = out + 8388608;
  if (ws_size < WS_NEED) return;
  char* ws = (char*)d_ws;
  unsigned short* xb     = (unsigned short*)(ws + OFF_XB);
  unsigned short* wqkvb  = (unsigned short*)(ws + OFF_WQKVB);
  unsigned short* wgateb = (unsigned short*)(ws + OFF_WGATEB);
  unsigned short* woutb  = (unsigned short*)(ws + OFF_WOUTB);
  unsigned short* qb     = (unsigned short*)(ws + OFF_QB);
  unsigned short* kb     = (unsigned short*)(ws + OFF_KB);
  unsigned short* vtb    = (unsigned short*)(ws + OFF_VTB);
  unsigned short* ktb    = (unsigned short*)(ws + OFF_YBUF);  // aliased (early lifetime)
  float*          kvc    = (float*)(ws + OFF_KVC);
  float*          attn   = (float*)(ws + OFF_ATTN);
  unsigned short* gate   = (unsigned short*)(ws + OFF_GATE);
  unsigned short* ybuf   = (unsigned short*)(ws + OFF_YBUF);  // late lifetime

  cast_f2b<<<8192,  256, 0, stream>>>(x,      xb,     8388608);
  cast_f2b<<<12288, 256, 0, stream>>>(w_qkv,  wqkvb,  12582912);
  cast_f2b<<<4096,  256, 0, stream>>>(w_gate, wgateb, 4194304);
  cast_f2b<<<4096,  256, 0, stream>>>(w_out,  woutb,  4194304);

  // fused qkv+gate GEMM: B = [w_qkv ; w_gate] rows 0..8191 (contiguous in ws)
  gemm_bt<1><<<dim3(64, 32), 256, 0, stream>>>(xb, wqkvb, 2048, 8192,
                                               qb, kb, vtb, ktb, gate, slope);

  chunk_kv_mfma<<<512, 256, 0, stream>>>(vtb, ktb, kvc);
  combine_kv   <<<256, 256, 0, stream>>>(kvc, past_kv, slope, out_kv);
  chunk_out_mfma<<<512, 256, 0, stream>>>(qb, kb, vtb, kvc, slope, attn);

  norm_gate<<<4096, 256, 0, stream>>>(attn, gate, norm_w, ybuf);
  gemm_bt<0><<<dim3(16, 32), 256, 0, stream>>>(ybuf, woutb, 2048, 2048,
                                               out, nullptr, nullptr, nullptr, nullptr, nullptr);
}

// Round 5
// 429.108 us; speedup vs baseline: 2.2384x; 1.1008x over previous
//
#include <hip/hip_runtime.h>

// ---------------------------------------------------------------------------
// MiniMax Lightning Attention (B=2,N=2048,D=2048,H=16,HD=128), fp32 in/out.
// cast->bf16 | 256^2 8-phase fused GEMM qkv+gate | tkv transpose (kT*lam, vT) |
// MFMA chunk_kv | combine | MFMA chunk_out | norm*gate | GEMM out (128^2).
// ---------------------------------------------------------------------------

typedef __attribute__((ext_vector_type(8))) short short8;
typedef __attribute__((ext_vector_type(4))) float f32x4;

__device__ __forceinline__ float blo(unsigned int u){ return __uint_as_float(u << 16); }
__device__ __forceinline__ float bhi(unsigned int u){ return __uint_as_float(u & 0xffff0000u); }
__device__ __forceinline__ unsigned short f2b(float f){
  unsigned int u = __float_as_uint(f);
  return (unsigned short)((u + 0x7fffu + ((u >> 16) & 1u)) >> 16);
}
__device__ __forceinline__ unsigned int pk2(float a, float b){
  return (unsigned int)f2b(a) | ((unsigned int)f2b(b) << 16);
}

#define GLOAD_LDS16(g, l) __builtin_amdgcn_global_load_lds( \
    (const __attribute__((address_space(1))) unsigned int*)(g), \
    (__attribute__((address_space(3))) unsigned int*)(l), 16, 0, 0)

// swizzled fragment read: row-major [128][128] bf16 tile, 16B slot ^= row&15
#define FRAG(buf, row, kt) (*(const short8*)&(buf)[(((row) << 7)) + \
    ((((((kt) << 2) + lk)) ^ ((row) & 15)) << 3)])

// ---------------- workspace layout (bytes) ----------------
#define OFF_XB     ((size_t)0)           // x bf16            [4096][2048]
#define OFF_WQKVB  ((size_t)16777216)    // w_qkv bf16        [6144][2048]
#define OFF_WGATEB ((size_t)41943040)    // w_gate bf16       [2048][2048] (contiguous after wqkv)
#define OFF_WOUTB  ((size_t)50331648)    // w_out bf16        [2048][2048]
#define OFF_QB     ((size_t)58720256)    // q bf16            [BH][2048][128]
#define OFF_KB     ((size_t)75497472)    // k bf16            [BH][2048][128]
#define OFF_VTB    ((size_t)92274688)    // v^T bf16          [BH][16][128 d][128 j]
#define OFF_KVC    ((size_t)109051904)   // transposed states f32 [BH][16][128 d][128 e]
#define OFF_ATTN   ((size_t)142606336)   // v row-major bf16 (early) / attn f32 (late)
#define OFF_GATE   ((size_t)176160768)   // sigmoid gate bf16 [4096][2048]
#define OFF_YBUF   ((size_t)192937984)   // kT*lam bf16 (early) / ybuf bf16 (late)
#define WS_NEED    ((size_t)209715200)

// ---------------- fp32 -> bf16 cast ----------------
__global__ __launch_bounds__(256)
void cast_f2b(const float* __restrict__ in, unsigned short* __restrict__ o, int n)
{
  int idx = (blockIdx.x * 256 + threadIdx.x) * 4;
  if (idx >= n) return;
  float4 v = *(const float4*)&in[idx];
  ushort4 u;
  u.x = f2b(v.x); u.y = f2b(v.y); u.z = f2b(v.z); u.w = f2b(v.w);
  *(ushort4*)&o[idx] = u;
}

// ---------------- 256^2 8-phase fused qkv+gate GEMM ----------------
// C[4096,8192] = A[4096,2048] * B[8192,2048]^T ; cols 0..6143 silu->q/k/v,
// cols 6144..8191 sigmoid->gate. BM=BN=256, BK=64, 8 waves (2Mx4N), dbuf LDS.
__global__ __launch_bounds__(512, 2)
void gemm256_qkvg(const unsigned short* __restrict__ A, const unsigned short* __restrict__ Bm,
                  const float* __restrict__ slope,
                  unsigned short* __restrict__ qo, unsigned short* __restrict__ ko,
                  unsigned short* __restrict__ vo, unsigned short* __restrict__ go)
{
  __shared__ unsigned short lds[65536];       // 128 KiB: [dbuf][A 16384 | B 16384]
  const int tid = threadIdx.x, lane = tid & 63, w = tid >> 6;
  const int wm = w >> 2, wn = w & 3;
  const int lr = lane & 15, kg = lane >> 4;

  // bijective XCD swizzle (nwg=512, 512%8==0)
  const int bid = blockIdx.x;
  const int swz = ((bid & 7) << 6) + (bid >> 3);
  const int mBase = (swz >> 5) << 8;          // 16 m-tiles
  const int nBase = (swz & 31) << 8;          // 32 n-tiles

  // stage one half (128 rows x 64 cols) of a K-tile: 2 x global_load_lds(16B)
  // LDS linear dest; global source pre-swizzled: slot sl holds col (sl^(r&7))*8
  auto stage = [&](const unsigned short* __restrict__ src, int rowBase, int k0,
                   unsigned short* lb, int half) {
#pragma unroll
    for (int s = 0; s < 2; ++s) {
      const int idx = (s << 9) + tid;
      const int r = idx >> 3, sl = idx & 7;
      GLOAD_LDS16(src + (size_t)(rowBase + (half << 7) + r) * 2048 + k0
                      + ((sl ^ (r & 7)) << 3),
                  lb + (half << 13) + (((s << 9) + (w << 6)) << 3));
    }
  };

  f32x4 acc[8][4];
#pragma unroll
  for (int m = 0; m < 8; ++m)
#pragma unroll
    for (int n = 0; n < 4; ++n) acc[m][n] = (f32x4){0.f, 0.f, 0.f, 0.f};

  const int NT = 32;                          // K=2048 / BK=64
  // prologue: tile 0 -> buf 0
  stage(A,  mBase, 0, lds,        0);
  stage(A,  mBase, 0, lds,        1);
  stage(Bm, nBase, 0, lds + 16384, 0);
  stage(Bm, nBase, 0, lds + 16384, 1);
  __syncthreads();

  for (int t = 0; t < NT; ++t) {
    unsigned short* Ab = lds + ((t & 1) << 15);
    unsigned short* Bb = Ab + 16384;
    unsigned short* An = lds + (((t & 1) ^ 1) << 15);
    unsigned short* Bn = An + 16384;
    const int k0n = (t + 1) << 6;
#pragma unroll
    for (int p = 0; p < 4; ++p) {
      if (t + 1 < NT) {                       // prefetch next tile, 1 half/phase
        if      (p == 0) stage(A,  mBase, k0n, An, 0);
        else if (p == 1) stage(A,  mBase, k0n, An, 1);
        else if (p == 2) stage(Bm, nBase, k0n, Bn, 0);
        else             stage(Bm, nBase, k0n, Bn, 1);
      }
      const int mh = p >> 1, nh = p & 1;      // quadrant of this wave's 128x64
      short8 af[4][2], bf[2][2];
#pragma unroll
      for (int m = 0; m < 4; ++m) {
        const int rA = (wm << 7) + (mh << 6) + (m << 4) + lr;
#pragma unroll
        for (int ks = 0; ks < 2; ++ks)
          af[m][ks] = *(const short8*)&Ab[(rA << 6) + ((((ks << 2) + kg) ^ (rA & 7)) << 3)];
      }
#pragma unroll
      for (int n = 0; n < 2; ++n) {
        const int rB = (wn << 6) + (nh << 5) + (n << 4) + lr;
#pragma unroll
        for (int ks = 0; ks < 2; ++ks)
          bf[n][ks] = *(const short8*)&Bb[(rB << 6) + ((((ks << 2) + kg) ^ (rB & 7)) << 3)];
      }
      __builtin_amdgcn_s_setprio(1);
#pragma unroll
      for (int m = 0; m < 4; ++m)
#pragma unroll
        for (int n = 0; n < 2; ++n)
#pragma unroll
          for (int ks = 0; ks < 2; ++ks)
            acc[(mh << 2) + m][(nh << 1) + n] =
              __builtin_amdgcn_mfma_f32_16x16x32_bf16(af[m][ks], bf[n][ks],
                  acc[(mh << 2) + m][(nh << 1) + n], 0, 0, 0);
      __builtin_amdgcn_s_setprio(0);
      if (p < 3) __builtin_amdgcn_s_barrier();  // phase align; loads stay in flight
    }
    __syncthreads();                            // dbuf handoff (vmcnt drain here only)
  }

  // ---- epilogue: per-wave-uniform region (64-col span within one 128 region) ----
  const int cb = nBase + (wn << 6);
  const int rowW = mBase + (wm << 7);
  if (cb >= 6144) {                             // gate: sigmoid
#pragma unroll
    for (int mi = 0; mi < 8; ++mi)
#pragma unroll
      for (int ni = 0; ni < 4; ++ni) {
        f32x4 v = acc[mi][ni];
        const int colg = cb - 6144 + (ni << 4) + lr;
#pragma unroll
        for (int r2 = 0; r2 < 4; ++r2) {
          const int row = rowW + (mi << 4) + (kg << 2) + r2;
          go[((size_t)row << 11) + colg] = f2b(1.f / (1.f + __expf(-v[r2])));
        }
      }
  } else {                                      // q/k/v: silu
    const int hh = cb / 384;
    const int rem = cb - hh * 384;
    const int sub = rem >> 7;
    const int db = rem & 127;
    unsigned short* dst = (sub == 0) ? qo : (sub == 1) ? ko : vo;
#pragma unroll
    for (int mi = 0; mi < 8; ++mi)
#pragma unroll
      for (int ni = 0; ni < 4; ++ni) {
        f32x4 v = acc[mi][ni];
        const int dd = db + (ni << 4) + lr;
#pragma unroll
        for (int r2 = 0; r2 < 4; ++r2) {
          const int row = rowW + (mi << 4) + (kg << 2) + r2;
          const int bb = row >> 11, nn = row & 2047;
          float sv = v[r2] / (1.f + __expf(-v[r2]));
          dst[(((size_t)((bb << 4) + hh) << 11) + nn) * 128 + dd] = f2b(sv);
        }
      }
  }
}

// ---------------- chunk transpose: k -> kT*lam^{127-j}, v -> vT ----------------
// per block: one (bh, cc) chunk [128 j][128 d] -> [128 d][128 j]
__global__ __launch_bounds__(256)
void tkv(const unsigned short* __restrict__ kg_, const unsigned short* __restrict__ vg_,
         const float* __restrict__ slope, unsigned short* __restrict__ kto,
         unsigned short* __restrict__ vto)
{
  __shared__ unsigned int T[8192];             // 32 KiB word-transposed tile
  __shared__ float lamt[128];
  const int blk = blockIdx.x;                  // bh*16 + cc
  const int h = (blk >> 4) & 15;
  const int tid = threadIdx.x;
  const size_t base = (size_t)blk << 14;
  if (tid < 128) lamt[tid] = __expf(-slope[h] * (float)(127 - tid));
#pragma unroll
  for (int pass = 0; pass < 2; ++pass) {
    const unsigned short* src = pass ? vg_ : kg_;
    __syncthreads();
    // load rows (coalesced) -> write word-transposed (swizzled, 2-way max)
#pragma unroll
    for (int it = 0; it < 4; ++it) {
      const int j = ((tid >> 4) << 1) + (it << 5);
      const int d0 = (tid & 15) << 3;
      uint4 a  = *(const uint4*)&src[base + (size_t)j * 128 + d0];
      uint4 b2 = *(const uint4*)&src[base + (size_t)(j + 1) * 128 + d0];
      const unsigned short* ap = (const unsigned short*)&a;
      const unsigned short* bp = (const unsigned short*)&b2;
      const int jp = j >> 1;
#pragma unroll
      for (int t2 = 0; t2 < 8; ++t2) {
        const int d = d0 + t2;
        T[(d << 6) + (jp ^ (((d >> 3) & 15) << 2))] =
            (unsigned int)ap[t2] | ((unsigned int)bp[t2] << 16);
      }
    }
    __syncthreads();
    // write transposed rows, coalesced 256B runs
#pragma unroll
    for (int it = 0; it < 8; ++it) {
      const int d = (tid >> 4) + (it << 4);
      const int jp0 = (tid & 15) << 2;
      uint4 u = *(const uint4*)&T[(d << 6) + (jp0 ^ (((d >> 3) & 15) << 2))];
      const int j0 = jp0 << 1;
      if (pass == 0) {
        u.x = pk2(blo(u.x) * lamt[j0],     bhi(u.x) * lamt[j0 + 1]);
        u.y = pk2(blo(u.y) * lamt[j0 + 2], bhi(u.y) * lamt[j0 + 3]);
        u.z = pk2(blo(u.z) * lamt[j0 + 4], bhi(u.z) * lamt[j0 + 5]);
        u.w = pk2(blo(u.w) * lamt[j0 + 6], bhi(u.w) * lamt[j0 + 7]);
        *(uint4*)&kto[base + ((size_t)d << 7) + j0] = u;
      } else {
        *(uint4*)&vto[base + ((size_t)d << 7) + j0] = u;
      }
    }
  }
}

// ---------------- 128^2 GEMM (out projection): C = A * B^T, f32 out ----------------
__global__ __launch_bounds__(256)
void gemm_out(const unsigned short* __restrict__ A, const unsigned short* __restrict__ Bm,
              int K, int Nn, float* __restrict__ o0)
{
  __shared__ unsigned short As[4096];
  __shared__ unsigned short Bs[4096];
  const int tid  = threadIdx.x;
  const int lane = tid & 63, w = tid >> 6;
  const int mBase = blockIdx.y << 7, nBase = blockIdx.x << 7;
  f32x4 acc[4][4];
#pragma unroll
  for (int m = 0; m < 4; ++m)
#pragma unroll
    for (int n = 0; n < 4; ++n) acc[m][n] = (f32x4){0.f,0.f,0.f,0.f};
  const int wr = w >> 1, wc = w & 1;
  const int rA = (wr << 6) + (lane & 15);
  const int cB = (wc << 6) + (lane & 15);
  const int kg = (lane >> 4) << 3;
  const int segBase = w << 7;
  const int nIter = K >> 5;
  for (int kt = 0; kt < nIter; ++kt) {
    const int k0 = kt << 5;
#pragma unroll
    for (int rep = 0; rep < 2; ++rep) {
      int seg = segBase + (rep << 6) + lane;
      int r  = seg >> 2;
      int c8 = (seg & 3) << 3;
      GLOAD_LDS16(A  + ((size_t)(mBase + r) * K + k0 + c8), &As[(segBase + (rep << 6)) << 3]);
      GLOAD_LDS16(Bm + ((size_t)(nBase + r) * K + k0 + c8), &Bs[(segBase + (rep << 6)) << 3]);
    }
    __syncthreads();
    short8 af[4], bfv[4];
#pragma unroll
    for (int m = 0; m < 4; ++m) af[m]  = *(const short8*)&As[((rA + (m << 4)) << 5) + kg];
#pragma unroll
    for (int n = 0; n < 4; ++n) bfv[n] = *(const short8*)&Bs[((cB + (n << 4)) << 5) + kg];
#pragma unroll
    for (int m = 0; m < 4; ++m)
#pragma unroll
      for (int n = 0; n < 4; ++n)
        acc[m][n] = __builtin_amdgcn_mfma_f32_16x16x32_bf16(af[m], bfv[n], acc[m][n], 0, 0, 0);
    __syncthreads();
  }
#pragma unroll
  for (int m = 0; m < 4; ++m)
#pragma unroll
    for (int n = 0; n < 4; ++n) {
      const int row0 = mBase + (wr << 6) + (m << 4) + ((lane >> 4) << 2);
      const int col  = nBase + (wc << 6) + (n << 4) + (lane & 15);
      f32x4 v = acc[m][n];
#pragma unroll
      for (int r2 = 0; r2 < 4; ++r2)
        o0[(size_t)(row0 + r2) * Nn + col] = v[r2];
    }
}

// ---------------- MFMA per-chunk local (transposed) KV ----------------
__global__ __launch_bounds__(256, 2)
void chunk_kv_mfma(const unsigned short* __restrict__ vtg,
                   const unsigned short* __restrict__ ktg,
                   float* __restrict__ KVc)
{
  __shared__ unsigned short VTs[16384], KTs[16384];
  const int blk = blockIdx.x;
  const int tid = threadIdx.x, lane = tid & 63, w = tid >> 6;
  const int wr = w >> 1, wc = w & 1, lr = lane & 15, lk = lane >> 4;
  const size_t base = (size_t)blk << 14;
#pragma unroll
  for (int it = 0; it < 8; ++it) {
    int segw = (w << 3) + it;
    int sg = (segw << 6) + lane;
    int r = sg >> 4, sl = sg & 15;
    size_t goff = ((size_t)r << 7) + (size_t)((sl ^ (r & 15)) << 3);
    GLOAD_LDS16(vtg + base + goff, &VTs[segw << 9]);
    GLOAD_LDS16(ktg + base + goff, &KTs[segw << 9]);
  }
  __syncthreads();
  f32x4 acc[4][4];
#pragma unroll
  for (int m = 0; m < 4; ++m)
#pragma unroll
    for (int n = 0; n < 4; ++n) acc[m][n] = (f32x4){0.f,0.f,0.f,0.f};
#pragma unroll
  for (int kt = 0; kt < 4; ++kt) {
    short8 af[4], bf2[4];
#pragma unroll
    for (int m = 0; m < 4; ++m) af[m]  = FRAG(VTs, (wr << 6) + (m << 4) + lr, kt);
#pragma unroll
    for (int n = 0; n < 4; ++n) bf2[n] = FRAG(KTs, (wc << 6) + (n << 4) + lr, kt);
#pragma unroll
    for (int m = 0; m < 4; ++m)
#pragma unroll
      for (int n = 0; n < 4; ++n)
        acc[m][n] = __builtin_amdgcn_mfma_f32_16x16x32_bf16(af[m], bf2[n], acc[m][n], 0, 0, 0);
  }
  float* outp = KVc + base;
#pragma unroll
  for (int m = 0; m < 4; ++m)
#pragma unroll
    for (int n = 0; n < 4; ++n)
#pragma unroll
      for (int r2 = 0; r2 < 4; ++r2)
        outp[(size_t)((wr << 6) + (m << 4) + (lk << 2) + r2) * 128
             + (wc << 6) + (n << 4) + lr] = acc[m][n][r2];
}

// ---------------- sequential chunk combine (transposed states) ----------------
__global__ __launch_bounds__(256)
void combine_kv(float* __restrict__ KVc, const float* __restrict__ past_kv,
                const float* __restrict__ slope, float* __restrict__ outkv)
{
  const int bh = blockIdx.x >> 3, slice = blockIdx.x & 7;
  const int h = bh & 15;
  const int tid = threadIdx.x;
  const float lamC = __expf(-slope[h] * 128.f);
  const int f0 = (slice << 11) + tid;
  float S[8];
  const float* pp = past_kv + ((size_t)bh << 14);
#pragma unroll
  for (int i = 0; i < 8; ++i) {
    int f = f0 + (i << 8);
    int d = f >> 7, e = f & 127;
    S[i] = pp[(e << 7) + d];
  }
  for (int cc = 0; cc < 16; ++cc) {
    float* p = KVc + ((((size_t)bh << 4) + cc) << 14);
#pragma unroll
    for (int i = 0; i < 8; ++i) {
      int f = f0 + (i << 8);
      float t = p[f];
      p[f] = S[i];
      S[i] = lamC * S[i] + t;
    }
  }
  float* op = outkv + ((size_t)bh << 14);
#pragma unroll
  for (int i = 0; i < 8; ++i) {
    int f = f0 + (i << 8);
    int d = f >> 7, e = f & 127;
    op[(e << 7) + d] = S[i];
  }
}

// ---------------- MFMA per-chunk outputs ----------------
__global__ __launch_bounds__(256, 1)
void chunk_out_mfma(const unsigned short* __restrict__ qg,
                    const unsigned short* __restrict__ kg,
                    const unsigned short* __restrict__ vtg,
                    const float* __restrict__ States,
                    const float* __restrict__ slope,
                    float* __restrict__ attn)
{
  __shared__ unsigned short Qs[16384], Ks[16384], VTs[16384], STs[16384];
  const int blk = blockIdx.x;
  const int cc = blk & 15, h = (blk >> 4) & 15, b = blk >> 8;
  const int tid = threadIdx.x, lane = tid & 63, w = tid >> 6;
  const int wr = w >> 1, wc = w & 1, lr = lane & 15, lk = lane >> 4;
  const size_t base = (size_t)blk << 14;
  const float s = slope[h];
#pragma unroll
  for (int it = 0; it < 8; ++it) {
    int segw = (w << 3) + it;
    int sg = (segw << 6) + lane;
    int r = sg >> 4, sl = sg & 15;
    size_t goff = ((size_t)r << 7) + (size_t)((sl ^ (r & 15)) << 3);
    GLOAD_LDS16(qg  + base + goff, &Qs[segw << 9]);
    GLOAD_LDS16(kg  + base + goff, &Ks[segw << 9]);
    GLOAD_LDS16(vtg + base + goff, &VTs[segw << 9]);
  }
  const float* Sg = States + base;
#pragma unroll
  for (int it = 0; it < 8; ++it) {
    int idx = ((it << 8) + tid) << 3;
    float4 a0 = *(const float4*)&Sg[idx];
    float4 a1 = *(const float4*)&Sg[idx + 4];
    int r = idx >> 7, c = idx & 127;
    int sl = (c >> 3) ^ (r & 15);
    uint4 u = make_uint4(pk2(a0.x,a0.y), pk2(a0.z,a0.w), pk2(a1.x,a1.y), pk2(a1.z,a1.w));
    *(uint4*)&STs[(r << 7) + (sl << 3)] = u;
  }
  __syncthreads();

  f32x4 Oa[4][4], Pa[4][4];
#pragma unroll
  for (int m = 0; m < 4; ++m)
#pragma unroll
    for (int n = 0; n < 4; ++n) { Oa[m][n] = (f32x4){0.f,0.f,0.f,0.f}; Pa[m][n] = (f32x4){0.f,0.f,0.f,0.f}; }

#pragma unroll
  for (int kt = 0; kt < 4; ++kt) {
    short8 qf[4], bst[4], bk[4];
#pragma unroll
    for (int m = 0; m < 4; ++m) qf[m] = FRAG(Qs, (wr << 6) + (m << 4) + lr, kt);
#pragma unroll
    for (int n = 0; n < 4; ++n) {
      int cn = (wc << 6) + (n << 4) + lr;
      bst[n] = FRAG(STs, cn, kt);
      bk[n]  = FRAG(Ks,  cn, kt);
    }
#pragma unroll
    for (int m = 0; m < 4; ++m)
#pragma unroll
      for (int n = 0; n < 4; ++n) {
        Oa[m][n] = __builtin_amdgcn_mfma_f32_16x16x32_bf16(qf[m], bst[n], Oa[m][n], 0, 0, 0);
        Pa[m][n] = __builtin_amdgcn_mfma_f32_16x16x32_bf16(qf[m], bk[n],  Pa[m][n], 0, 0, 0);
      }
  }

  float emi[16];
#pragma unroll
  for (int m = 0; m < 4; ++m)
#pragma unroll
    for (int r2 = 0; r2 < 4; ++r2)
      emi[(m << 2) + r2] = __expf(-s * (float)((wr << 6) + (m << 4) + (lk << 2) + r2));
  const float lam1 = __expf(-s);
  float epj[4];
#pragma unroll
  for (int n = 0; n < 4; ++n)
    epj[n] = __expf(s * (float)((wc << 6) + (n << 4) + lr));

#pragma unroll
  for (int m = 0; m < 4; ++m)
#pragma unroll
    for (int n = 0; n < 4; ++n) {
      const int j = (wc << 6) + (n << 4) + lr;
#pragma unroll
      for (int r2 = 0; r2 < 4; ++r2) {
        const int i = (wr << 6) + (m << 4) + (lk << 2) + r2;
        Oa[m][n][r2] *= emi[(m << 2) + r2] * lam1;
        float pv = Pa[m][n][r2] * emi[(m << 2) + r2] * epj[n];
        Pa[m][n][r2] = (i >= j) ? pv : 0.f;
      }
    }
  __syncthreads();

#pragma unroll
  for (int m = 0; m < 4; ++m)
#pragma unroll
    for (int n = 0; n < 4; ++n) {
      const int j = (wc << 6) + (n << 4) + lr;
#pragma unroll
      for (int r2 = 0; r2 < 4; ++r2) {
        const int i = (wr << 6) + (m << 4) + (lk << 2) + r2;
        const int sl = (j >> 3) ^ (i & 15);
        Ks[(i << 7) + (sl << 3) + (j & 7)] = f2b(Pa[m][n][r2]);
      }
    }
  __syncthreads();

#pragma unroll
  for (int kt = 0; kt < 4; ++kt) {
    short8 pf[4], vf[4];
#pragma unroll
    for (int m = 0; m < 4; ++m) pf[m] = FRAG(Ks,  (wr << 6) + (m << 4) + lr, kt);
#pragma unroll
    for (int n = 0; n < 4; ++n) vf[n] = FRAG(VTs, (wc << 6) + (n << 4) + lr, kt);
#pragma unroll
    for (int m = 0; m < 4; ++m)
#pragma unroll
      for (int n = 0; n < 4; ++n)
        Oa[m][n] = __builtin_amdgcn_mfma_f32_16x16x32_bf16(pf[m], vf[n], Oa[m][n], 0, 0, 0);
  }

#pragma unroll
  for (int m = 0; m < 4; ++m)
#pragma unroll
    for (int n = 0; n < 4; ++n) {
      const int c = (wc << 6) + (n << 4) + lr;
#pragma unroll
      for (int r2 = 0; r2 < 4; ++r2) {
        const int i = (wr << 6) + (m << 4) + (lk << 2) + r2;
        attn[(((size_t)((b << 11) + (cc << 7) + i)) << 11) + (h << 7) + c] = Oa[m][n][r2];
      }
    }
}

// ---------------- RMSNorm * norm_w * sigmoid-gate -> bf16 ----------------
__global__ __launch_bounds__(256)
void norm_gate(const float* __restrict__ attn, const unsigned short* __restrict__ gateb,
               const float* __restrict__ normw, unsigned short* __restrict__ ybuf)
{
  const int row = blockIdx.x;
  const int tid = threadIdx.x;
  const float* ar = attn + ((size_t)row << 11);
  float4 v0 = *(const float4*)&ar[tid * 8];
  float4 v1 = *(const float4*)&ar[tid * 8 + 4];
  float ss = v0.x*v0.x + v0.y*v0.y + v0.z*v0.z + v0.w*v0.w
           + v1.x*v1.x + v1.y*v1.y + v1.z*v1.z + v1.w*v1.w;
#pragma unroll
  for (int off = 32; off > 0; off >>= 1) ss += __shfl_down(ss, off);
  __shared__ float red[4];
  if ((tid & 63) == 0) red[tid >> 6] = ss;
  __syncthreads();
  float tot = red[0] + red[1] + red[2] + red[3];
  float scale = rsqrtf(tot * (1.f / 2048.f) + 1e-6f);
  uint4 gg = *(const uint4*)&gateb[((size_t)row << 11) + tid * 8];
  float4 w0 = *(const float4*)&normw[tid * 8];
  float4 w1 = *(const float4*)&normw[tid * 8 + 4];
  ushort4 o0, o1;
  o0.x = f2b(v0.x * scale * w0.x * blo(gg.x));
  o0.y = f2b(v0.y * scale * w0.y * bhi(gg.x));
  o0.z = f2b(v0.z * scale * w0.z * blo(gg.y));
  o0.w = f2b(v0.w * scale * w0.w * bhi(gg.y));
  o1.x = f2b(v1.x * scale * w1.x * blo(gg.z));
  o1.y = f2b(v1.y * scale * w1.y * bhi(gg.z));
  o1.z = f2b(v1.z * scale * w1.z * blo(gg.w));
  o1.w = f2b(v1.w * scale * w1.w * bhi(gg.w));
  *(ushort4*)&ybuf[((size_t)row << 11) + tid * 8]     = o0;
  *(ushort4*)&ybuf[((size_t)row << 11) + tid * 8 + 4] = o1;
}

// ---------------------------------------------------------------------------
extern "C" void kernel_launch(void* const* d_in, const int* in_sizes, int n_in,
                              void* d_out, int out_size, void* d_ws, size_t ws_size,
                              hipStream_t stream)
{
  const float* x       = (const float*)d_in[0];
  const float* past_kv = (const float*)d_in[1];
  const float* slope   = (const float*)d_in[2];
  const float* w_qkv   = (const float*)d_in[3];
  const float* w_gate  = (const float*)d_in[4];
  const float* w_out   = (const float*)d_in[5];
  const float* norm_w  = (const float*)d_in[6];
  float* out    = (float*)d_out;
  float* out_kv = out + 8388608;
  if (ws_size < WS_NEED) return;
  char* ws = (char*)d_ws;
  unsigned short* xb     = (unsigned short*)(ws + OFF_XB);
  unsigned short* wqkvb  = (unsigned short*)(ws + OFF_WQKVB);
  unsigned short* wgateb = (unsigned short*)(ws + OFF_WGATEB);
  unsigned short* woutb  = (unsigned short*)(ws + OFF_WOUTB);
  unsigned short* qb     = (unsigned short*)(ws + OFF_QB);
  unsigned short* kb     = (unsigned short*)(ws + OFF_KB);
  unsigned short* vtb    = (unsigned short*)(ws + OFF_VTB);
  unsigned short* vrow   = (unsigned short*)(ws + OFF_ATTN);  // early lifetime
  unsigned short* ktb    = (unsigned short*)(ws + OFF_YBUF);  // early lifetime
  float*          kvc    = (float*)(ws + OFF_KVC);
  float*          attn   = (float*)(ws + OFF_ATTN);           // late lifetime
  unsigned short* gate   = (unsigned short*)(ws + OFF_GATE);
  unsigned short* ybuf   = (unsigned short*)(ws + OFF_YBUF);  // late lifetime

  cast_f2b<<<8192,  256, 0, stream>>>(x,      xb,     8388608);
  cast_f2b<<<12288, 256, 0, stream>>>(w_qkv,  wqkvb,  12582912);
  cast_f2b<<<4096,  256, 0, stream>>>(w_gate, wgateb, 4194304);
  cast_f2b<<<4096,  256, 0, stream>>>(w_out,  woutb,  4194304);

  // fused qkv+gate GEMM: B = [w_qkv ; w_gate] rows 0..8191 (contiguous in ws)
  gemm256_qkvg<<<512, 512, 0, stream>>>(xb, wqkvb, slope, qb, kb, vrow, gate);

  tkv<<<512, 256, 0, stream>>>(kb, vrow, slope, ktb, vtb);

  chunk_kv_mfma <<<512, 256, 0, stream>>>(vtb, ktb, kvc);
  combine_kv    <<<256, 256, 0, stream>>>(kvc, past_kv, slope, out_kv);
  chunk_out_mfma<<<512, 256, 0, stream>>>(qb, kb, vtb, kvc, slope, attn);

  norm_gate<<<4096, 256, 0, stream>>>(attn, gate, norm_w, ybuf);
  gemm_out<<<dim3(16, 32), 256, 0, stream>>>(ybuf, woutb, 2048, 2048, out);
}

// Round 6
// 419.417 us; speedup vs baseline: 2.2901x; 1.0231x over previous
//
#include <hip/hip_runtime.h>

// ---------------------------------------------------------------------------
// MiniMax Lightning Attention (B=2,N=2048,D=2048,H=16,HD=128), fp32 in/out.
// cast->bf16 | 256^2 counted-vmcnt 4-phase fused GEMM qkv+gate | tkv transpose |
// MFMA chunk_kv | combine | MFMA chunk_out | norm*gate | GEMM out (128^2).
// ---------------------------------------------------------------------------

typedef __attribute__((ext_vector_type(8))) short short8;
typedef __attribute__((ext_vector_type(4))) float f32x4;

__device__ __forceinline__ float blo(unsigned int u){ return __uint_as_float(u << 16); }
__device__ __forceinline__ float bhi(unsigned int u){ return __uint_as_float(u & 0xffff0000u); }
__device__ __forceinline__ unsigned short f2b(float f){
  unsigned int u = __float_as_uint(f);
  return (unsigned short)((u + 0x7fffu + ((u >> 16) & 1u)) >> 16);
}
__device__ __forceinline__ unsigned int pk2(float a, float b){
  return (unsigned int)f2b(a) | ((unsigned int)f2b(b) << 16);
}

#define GLOAD_LDS16(g, l) __builtin_amdgcn_global_load_lds( \
    (const __attribute__((address_space(1))) unsigned int*)(g), \
    (__attribute__((address_space(3))) unsigned int*)(l), 16, 0, 0)

#define VMCNT(N) asm volatile("s_waitcnt vmcnt(" #N ")" ::: "memory")
#define SBAR()   __builtin_amdgcn_s_barrier()

// swizzled fragment read: row-major [128][128] bf16 tile, 16B slot ^= row&15
#define FRAG(buf, row, kt) (*(const short8*)&(buf)[(((row) << 7)) + \
    ((((((kt) << 2) + lk)) ^ ((row) & 15)) << 3)])

// ---------------- workspace layout (bytes) ----------------
#define OFF_XB     ((size_t)0)           // x bf16            [4096][2048]
#define OFF_WQKVB  ((size_t)16777216)    // w_qkv bf16        [6144][2048]
#define OFF_WGATEB ((size_t)41943040)    // w_gate bf16       [2048][2048] (contiguous after wqkv)
#define OFF_WOUTB  ((size_t)50331648)    // w_out bf16        [2048][2048]
#define OFF_QB     ((size_t)58720256)    // q bf16            [BH][2048][128]
#define OFF_KB     ((size_t)75497472)    // k bf16            [BH][2048][128]
#define OFF_VTB    ((size_t)92274688)    // v^T bf16          [BH][16][128 d][128 j]
#define OFF_KVC    ((size_t)109051904)   // transposed states f32 [BH][16][128 d][128 e]
#define OFF_ATTN   ((size_t)142606336)   // v row-major bf16 (early) / attn f32 (late)
#define OFF_GATE   ((size_t)176160768)   // sigmoid gate bf16 [4096][2048]
#define OFF_YBUF   ((size_t)192937984)   // kT*lam bf16 (early) / ybuf bf16 (late)
#define WS_NEED    ((size_t)209715200)

// ---------------- fp32 -> bf16 cast ----------------
__global__ __launch_bounds__(256)
void cast_f2b(const float* __restrict__ in, unsigned short* __restrict__ o, int n)
{
  int idx = (blockIdx.x * 256 + threadIdx.x) * 4;
  if (idx >= n) return;
  float4 v = *(const float4*)&in[idx];
  ushort4 u;
  u.x = f2b(v.x); u.y = f2b(v.y); u.z = f2b(v.z); u.w = f2b(v.w);
  *(ushort4*)&o[idx] = u;
}

// ---------------- 256^2 counted-vmcnt fused qkv+gate GEMM ----------------
// C[4096,8192] = A[4096,2048] * B[8192,2048]^T ; cols 0..6143 silu->q/k/v,
// cols 6144..8191 sigmoid->gate. BM=BN=256, BK=64, 8 waves (2Mx4N), dbuf LDS.
// Phase p -> (A-half,B-half): (0,0) (0,1) (1,1) (1,0); stage order A0,B0,B1,A1.
// vmcnt(4) per phase (never 0 in main loop); last tile peeled with 4/2/0.
__global__ __launch_bounds__(512, 2)
void gemm256_qkvg(const unsigned short* __restrict__ A, const unsigned short* __restrict__ Bm,
                  const float* __restrict__ slope,
                  unsigned short* __restrict__ qo, unsigned short* __restrict__ ko,
                  unsigned short* __restrict__ vo, unsigned short* __restrict__ go)
{
  __shared__ unsigned short lds[65536];       // 128 KiB: [dbuf][A 16384 | B 16384]
  const int tid = threadIdx.x, lane = tid & 63, w = tid >> 6;
  const int wm = w >> 2, wn = w & 3;
  const int lr = lane & 15, kg = lane >> 4;

  // XCD remap: each XCD owns an 8m x 8n super-block (fetch ~16MB/XCD)
  const int bid = blockIdx.x;
  const int x = bid & 7, idx0 = bid >> 3;
  const int mt = ((x >> 2) << 3) + (idx0 >> 3);   // 0..15
  const int nt = ((x & 3) << 3) + (idx0 & 7);     // 0..31
  const int mBase = mt << 8, nBase = nt << 8;

  // stage one half (128 rows x 64 cols): 2 x global_load_lds(16B)/thread.
  // LDS linear dest; global source pre-swizzled: slot sl holds col (sl^(r&7))*8
  auto stage = [&](const unsigned short* __restrict__ src, int rowBase, int k0,
                   unsigned short* lb, int half) {
#pragma unroll
    for (int s = 0; s < 2; ++s) {
      const int idx2 = (s << 9) + tid;
      const int r = idx2 >> 3, sl = idx2 & 7;
      GLOAD_LDS16(src + (size_t)(rowBase + (half << 7) + r) * 2048 + k0
                      + ((sl ^ (r & 7)) << 3),
                  lb + (half << 13) + (((s << 9) + (w << 6)) << 3));
    }
  };

  f32x4 acc[8][4];
#pragma unroll
  for (int m = 0; m < 8; ++m)
#pragma unroll
    for (int n = 0; n < 4; ++n) acc[m][n] = (f32x4){0.f, 0.f, 0.f, 0.f};

  auto loadA = [&](short8 af[4][2], const unsigned short* Ab, int a) {
#pragma unroll
    for (int m = 0; m < 4; ++m) {
      const int rA = (a << 7) + (wm << 6) + (m << 4) + lr;
#pragma unroll
      for (int ks = 0; ks < 2; ++ks)
        af[m][ks] = *(const short8*)&Ab[(rA << 6) + ((((ks << 2) + kg) ^ (rA & 7)) << 3)];
    }
  };
  auto loadB = [&](short8 bf[2][2], const unsigned short* Bb, int b) {
#pragma unroll
    for (int n = 0; n < 2; ++n) {
      const int rB = (b << 7) + (wn << 5) + (n << 4) + lr;
#pragma unroll
      for (int ks = 0; ks < 2; ++ks)
        bf[n][ks] = *(const short8*)&Bb[(rB << 6) + ((((ks << 2) + kg) ^ (rB & 7)) << 3)];
    }
  };
  auto mfma8 = [&](short8 af[4][2], short8 bf[2][2], int a, int b) {
    __builtin_amdgcn_s_setprio(1);
#pragma unroll
    for (int m = 0; m < 4; ++m)
#pragma unroll
      for (int n = 0; n < 2; ++n)
#pragma unroll
        for (int ks = 0; ks < 2; ++ks)
          acc[(a << 2) + m][(b << 1) + n] = __builtin_amdgcn_mfma_f32_16x16x32_bf16(
              af[m][ks], bf[n][ks], acc[(a << 2) + m][(b << 1) + n], 0, 0, 0);
    __builtin_amdgcn_s_setprio(0);
  };

  const int NT = 32;                          // K=2048 / BK=64
  // prologue: tile 0 -> buf 0, order A0,B0,B1,A1 (8 loads/thread in flight)
  stage(A,  mBase, 0, lds,         0);
  stage(Bm, nBase, 0, lds + 16384, 0);
  stage(Bm, nBase, 0, lds + 16384, 1);
  stage(A,  mBase, 0, lds,         1);

  for (int t = 0; t < NT - 1; ++t) {
    unsigned short* Ab = lds + ((t & 1) << 15);
    unsigned short* Bb = Ab + 16384;
    unsigned short* An = lds + (((t & 1) ^ 1) << 15);
    unsigned short* Bn = An + 16384;
    const int k0n = (t + 1) << 6;
    short8 af[4][2], bf0[2][2], bf1[2][2];
    // phase 0: (A0,B0)
    VMCNT(4); SBAR();
    loadA(af, Ab, 0); loadB(bf0, Bb, 0);
    stage(A, mBase, k0n, An, 0);
    mfma8(af, bf0, 0, 0);
    // phase 1: (A0,B1)
    VMCNT(4); SBAR();
    loadB(bf1, Bb, 1);
    stage(Bm, nBase, k0n, Bn, 0);
    mfma8(af, bf1, 0, 1);
    // phase 2: (A1,B1)
    VMCNT(4); SBAR();
    loadA(af, Ab, 1);
    stage(Bm, nBase, k0n, Bn, 1);
    mfma8(af, bf1, 1, 1);
    // phase 3: (A1,B0)
    SBAR();
    stage(A, mBase, k0n, An, 1);
    mfma8(af, bf0, 1, 0);
  }
  { // peeled last tile (NT-1 odd -> buf 1); waits drain 4/2/0
    unsigned short* Ab = lds + (((NT - 1) & 1) << 15);
    unsigned short* Bb = Ab + 16384;
    short8 af[4][2], bf0[2][2], bf1[2][2];
    VMCNT(4); SBAR();
    loadA(af, Ab, 0); loadB(bf0, Bb, 0);
    mfma8(af, bf0, 0, 0);
    VMCNT(2); SBAR();
    loadB(bf1, Bb, 1);
    mfma8(af, bf1, 0, 1);
    VMCNT(0); SBAR();
    loadA(af, Ab, 1);
    mfma8(af, bf1, 1, 1);
    SBAR();
    mfma8(af, bf0, 1, 0);
  }

  // ---- epilogue: acc[(a<<2)+m][(b<<1)+n] ->
  //  row = mBase + a*128 + wm*64 + m*16 + kg*4 + r2
  //  col = nBase + b*128 + wn*32 + n*16 + lr
#pragma unroll
  for (int b2 = 0; b2 < 2; ++b2) {
    const int cb = nBase + (b2 << 7);           // 128-col region base
    if (cb >= 6144) {                           // gate: sigmoid
      const int colg0 = cb - 6144 + (wn << 5);
#pragma unroll
      for (int a = 0; a < 2; ++a)
#pragma unroll
        for (int m = 0; m < 4; ++m)
#pragma unroll
          for (int n = 0; n < 2; ++n) {
            f32x4 v = acc[(a << 2) + m][(b2 << 1) + n];
            const int col = colg0 + (n << 4) + lr;
#pragma unroll
            for (int r2 = 0; r2 < 4; ++r2) {
              const int row = mBase + (a << 7) + (wm << 6) + (m << 4) + (kg << 2) + r2;
              go[((size_t)row << 11) + col] = f2b(1.f / (1.f + __expf(-v[r2])));
            }
          }
    } else {                                    // q/k/v: silu
      const int hh = cb / 384;
      const int rem = cb - hh * 384;
      const int sub = rem >> 7;
      const int db = (rem & 127) + (wn << 5);
      unsigned short* dst = (sub == 0) ? qo : (sub == 1) ? ko : vo;
#pragma unroll
      for (int a = 0; a < 2; ++a)
#pragma unroll
        for (int m = 0; m < 4; ++m)
#pragma unroll
          for (int n = 0; n < 2; ++n) {
            f32x4 v = acc[(a << 2) + m][(b2 << 1) + n];
            const int dd = db + (n << 4) + lr;
#pragma unroll
            for (int r2 = 0; r2 < 4; ++r2) {
              const int row = mBase + (a << 7) + (wm << 6) + (m << 4) + (kg << 2) + r2;
              const int bb = row >> 11, nn = row & 2047;
              float sv = v[r2] / (1.f + __expf(-v[r2]));
              dst[(((size_t)((bb << 4) + hh) << 11) + nn) * 128 + dd] = f2b(sv);
            }
          }
    }
  }
}

// ---------------- chunk transpose: k -> kT*lam^{127-j}, v -> vT ----------------
__global__ __launch_bounds__(256)
void tkv(const unsigned short* __restrict__ kg_, const unsigned short* __restrict__ vg_,
         const float* __restrict__ slope, unsigned short* __restrict__ kto,
         unsigned short* __restrict__ vto)
{
  __shared__ unsigned int T[8192];             // 32 KiB word-transposed tile
  __shared__ float lamt[128];
  const int blk = blockIdx.x;                  // bh*16 + cc
  const int h = (blk >> 4) & 15;
  const int tid = threadIdx.x;
  const size_t base = (size_t)blk << 14;
  if (tid < 128) lamt[tid] = __expf(-slope[h] * (float)(127 - tid));
#pragma unroll
  for (int pass = 0; pass < 2; ++pass) {
    const unsigned short* src = pass ? vg_ : kg_;
    __syncthreads();
#pragma unroll
    for (int it = 0; it < 4; ++it) {
      const int j = ((tid >> 4) << 1) + (it << 5);
      const int d0 = (tid & 15) << 3;
      uint4 a  = *(const uint4*)&src[base + (size_t)j * 128 + d0];
      uint4 b2 = *(const uint4*)&src[base + (size_t)(j + 1) * 128 + d0];
      const unsigned short* ap = (const unsigned short*)&a;
      const unsigned short* bp = (const unsigned short*)&b2;
      const int jp = j >> 1;
#pragma unroll
      for (int t2 = 0; t2 < 8; ++t2) {
        const int d = d0 + t2;
        T[(d << 6) + (jp ^ (((d >> 3) & 15) << 2))] =
            (unsigned int)ap[t2] | ((unsigned int)bp[t2] << 16);
      }
    }
    __syncthreads();
#pragma unroll
    for (int it = 0; it < 8; ++it) {
      const int d = (tid >> 4) + (it << 4);
      const int jp0 = (tid & 15) << 2;
      uint4 u = *(const uint4*)&T[(d << 6) + (jp0 ^ (((d >> 3) & 15) << 2))];
      const int j0 = jp0 << 1;
      if (pass == 0) {
        u.x = pk2(blo(u.x) * lamt[j0],     bhi(u.x) * lamt[j0 + 1]);
        u.y = pk2(blo(u.y) * lamt[j0 + 2], bhi(u.y) * lamt[j0 + 3]);
        u.z = pk2(blo(u.z) * lamt[j0 + 4], bhi(u.z) * lamt[j0 + 5]);
        u.w = pk2(blo(u.w) * lamt[j0 + 6], bhi(u.w) * lamt[j0 + 7]);
        *(uint4*)&kto[base + ((size_t)d << 7) + j0] = u;
      } else {
        *(uint4*)&vto[base + ((size_t)d << 7) + j0] = u;
      }
    }
  }
}

// ---------------- 128^2 GEMM (out projection): C = A * B^T, f32 out ----------------
__global__ __launch_bounds__(256)
void gemm_out(const unsigned short* __restrict__ A, const unsigned short* __restrict__ Bm,
              int K, int Nn, float* __restrict__ o0)
{
  __shared__ unsigned short As[4096];
  __shared__ unsigned short Bs[4096];
  const int tid  = threadIdx.x;
  const int lane = tid & 63, w = tid >> 6;
  const int mBase = blockIdx.y << 7, nBase = blockIdx.x << 7;
  f32x4 acc[4][4];
#pragma unroll
  for (int m = 0; m < 4; ++m)
#pragma unroll
    for (int n = 0; n < 4; ++n) acc[m][n] = (f32x4){0.f,0.f,0.f,0.f};
  const int wr = w >> 1, wc = w & 1;
  const int rA = (wr << 6) + (lane & 15);
  const int cB = (wc << 6) + (lane & 15);
  const int kg = (lane >> 4) << 3;
  const int segBase = w << 7;
  const int nIter = K >> 5;
  for (int kt = 0; kt < nIter; ++kt) {
    const int k0 = kt << 5;
#pragma unroll
    for (int rep = 0; rep < 2; ++rep) {
      int seg = segBase + (rep << 6) + lane;
      int r  = seg >> 2;
      int c8 = (seg & 3) << 3;
      GLOAD_LDS16(A  + ((size_t)(mBase + r) * K + k0 + c8), &As[(segBase + (rep << 6)) << 3]);
      GLOAD_LDS16(Bm + ((size_t)(nBase + r) * K + k0 + c8), &Bs[(segBase + (rep << 6)) << 3]);
    }
    __syncthreads();
    short8 af[4], bfv[4];
#pragma unroll
    for (int m = 0; m < 4; ++m) af[m]  = *(const short8*)&As[((rA + (m << 4)) << 5) + kg];
#pragma unroll
    for (int n = 0; n < 4; ++n) bfv[n] = *(const short8*)&Bs[((cB + (n << 4)) << 5) + kg];
#pragma unroll
    for (int m = 0; m < 4; ++m)
#pragma unroll
      for (int n = 0; n < 4; ++n)
        acc[m][n] = __builtin_amdgcn_mfma_f32_16x16x32_bf16(af[m], bfv[n], acc[m][n], 0, 0, 0);
    __syncthreads();
  }
#pragma unroll
  for (int m = 0; m < 4; ++m)
#pragma unroll
    for (int n = 0; n < 4; ++n) {
      const int row0 = mBase + (wr << 6) + (m << 4) + ((lane >> 4) << 2);
      const int col  = nBase + (wc << 6) + (n << 4) + (lane & 15);
      f32x4 v = acc[m][n];
#pragma unroll
      for (int r2 = 0; r2 < 4; ++r2)
        o0[(size_t)(row0 + r2) * Nn + col] = v[r2];
    }
}

// ---------------- MFMA per-chunk local (transposed) KV ----------------
__global__ __launch_bounds__(256, 2)
void chunk_kv_mfma(const unsigned short* __restrict__ vtg,
                   const unsigned short* __restrict__ ktg,
                   float* __restrict__ KVc)
{
  __shared__ unsigned short VTs[16384], KTs[16384];
  const int blk = blockIdx.x;
  const int tid = threadIdx.x, lane = tid & 63, w = tid >> 6;
  const int wr = w >> 1, wc = w & 1, lr = lane & 15, lk = lane >> 4;
  const size_t base = (size_t)blk << 14;
#pragma unroll
  for (int it = 0; it < 8; ++it) {
    int segw = (w << 3) + it;
    int sg = (segw << 6) + lane;
    int r = sg >> 4, sl = sg & 15;
    size_t goff = ((size_t)r << 7) + (size_t)((sl ^ (r & 15)) << 3);
    GLOAD_LDS16(vtg + base + goff, &VTs[segw << 9]);
    GLOAD_LDS16(ktg + base + goff, &KTs[segw << 9]);
  }
  __syncthreads();
  f32x4 acc[4][4];
#pragma unroll
  for (int m = 0; m < 4; ++m)
#pragma unroll
    for (int n = 0; n < 4; ++n) acc[m][n] = (f32x4){0.f,0.f,0.f,0.f};
#pragma unroll
  for (int kt = 0; kt < 4; ++kt) {
    short8 af[4], bf2[4];
#pragma unroll
    for (int m = 0; m < 4; ++m) af[m]  = FRAG(VTs, (wr << 6) + (m << 4) + lr, kt);
#pragma unroll
    for (int n = 0; n < 4; ++n) bf2[n] = FRAG(KTs, (wc << 6) + (n << 4) + lr, kt);
#pragma unroll
    for (int m = 0; m < 4; ++m)
#pragma unroll
      for (int n = 0; n < 4; ++n)
        acc[m][n] = __builtin_amdgcn_mfma_f32_16x16x32_bf16(af[m], bf2[n], acc[m][n], 0, 0, 0);
  }
  float* outp = KVc + base;
#pragma unroll
  for (int m = 0; m < 4; ++m)
#pragma unroll
    for (int n = 0; n < 4; ++n)
#pragma unroll
      for (int r2 = 0; r2 < 4; ++r2)
        outp[(size_t)((wr << 6) + (m << 4) + (lk << 2) + r2) * 128
             + (wc << 6) + (n << 4) + lr] = acc[m][n][r2];
}

// ---------------- sequential chunk combine (transposed states) ----------------
__global__ __launch_bounds__(256)
void combine_kv(float* __restrict__ KVc, const float* __restrict__ past_kv,
                const float* __restrict__ slope, float* __restrict__ outkv)
{
  const int bh = blockIdx.x >> 3, slice = blockIdx.x & 7;
  const int h = bh & 15;
  const int tid = threadIdx.x;
  const float lamC = __expf(-slope[h] * 128.f);
  const int f0 = (slice << 11) + tid;
  float S[8];
  const float* pp = past_kv + ((size_t)bh << 14);
#pragma unroll
  for (int i = 0; i < 8; ++i) {
    int f = f0 + (i << 8);
    int d = f >> 7, e = f & 127;
    S[i] = pp[(e << 7) + d];
  }
  for (int cc = 0; cc < 16; ++cc) {
    float* p = KVc + ((((size_t)bh << 4) + cc) << 14);
#pragma unroll
    for (int i = 0; i < 8; ++i) {
      int f = f0 + (i << 8);
      float t = p[f];
      p[f] = S[i];
      S[i] = lamC * S[i] + t;
    }
  }
  float* op = outkv + ((size_t)bh << 14);
#pragma unroll
  for (int i = 0; i < 8; ++i) {
    int f = f0 + (i << 8);
    int d = f >> 7, e = f & 127;
    op[(e << 7) + d] = S[i];
  }
}

// ---------------- MFMA per-chunk outputs ----------------
__global__ __launch_bounds__(256, 1)
void chunk_out_mfma(const unsigned short* __restrict__ qg,
                    const unsigned short* __restrict__ kg,
                    const unsigned short* __restrict__ vtg,
                    const float* __restrict__ States,
                    const float* __restrict__ slope,
                    float* __restrict__ attn)
{
  __shared__ unsigned short Qs[16384], Ks[16384], VTs[16384], STs[16384];
  const int blk = blockIdx.x;
  const int cc = blk & 15, h = (blk >> 4) & 15, b = blk >> 8;
  const int tid = threadIdx.x, lane = tid & 63, w = tid >> 6;
  const int wr = w >> 1, wc = w & 1, lr = lane & 15, lk = lane >> 4;
  const size_t base = (size_t)blk << 14;
  const float s = slope[h];
#pragma unroll
  for (int it = 0; it < 8; ++it) {
    int segw = (w << 3) + it;
    int sg = (segw << 6) + lane;
    int r = sg >> 4, sl = sg & 15;
    size_t goff = ((size_t)r << 7) + (size_t)((sl ^ (r & 15)) << 3);
    GLOAD_LDS16(qg  + base + goff, &Qs[segw << 9]);
    GLOAD_LDS16(kg  + base + goff, &Ks[segw << 9]);
    GLOAD_LDS16(vtg + base + goff, &VTs[segw << 9]);
  }
  const float* Sg = States + base;
#pragma unroll
  for (int it = 0; it < 8; ++it) {
    int idx = ((it << 8) + tid) << 3;
    float4 a0 = *(const float4*)&Sg[idx];
    float4 a1 = *(const float4*)&Sg[idx + 4];
    int r = idx >> 7, c = idx & 127;
    int sl = (c >> 3) ^ (r & 15);
    uint4 u = make_uint4(pk2(a0.x,a0.y), pk2(a0.z,a0.w), pk2(a1.x,a1.y), pk2(a1.z,a1.w));
    *(uint4*)&STs[(r << 7) + (sl << 3)] = u;
  }
  __syncthreads();

  f32x4 Oa[4][4], Pa[4][4];
#pragma unroll
  for (int m = 0; m < 4; ++m)
#pragma unroll
    for (int n = 0; n < 4; ++n) { Oa[m][n] = (f32x4){0.f,0.f,0.f,0.f}; Pa[m][n] = (f32x4){0.f,0.f,0.f,0.f}; }

#pragma unroll
  for (int kt = 0; kt < 4; ++kt) {
    short8 qf[4], bst[4], bk[4];
#pragma unroll
    for (int m = 0; m < 4; ++m) qf[m] = FRAG(Qs, (wr << 6) + (m << 4) + lr, kt);
#pragma unroll
    for (int n = 0; n < 4; ++n) {
      int cn = (wc << 6) + (n << 4) + lr;
      bst[n] = FRAG(STs, cn, kt);
      bk[n]  = FRAG(Ks,  cn, kt);
    }
#pragma unroll
    for (int m = 0; m < 4; ++m)
#pragma unroll
      for (int n = 0; n < 4; ++n) {
        Oa[m][n] = __builtin_amdgcn_mfma_f32_16x16x32_bf16(qf[m], bst[n], Oa[m][n], 0, 0, 0);
        Pa[m][n] = __builtin_amdgcn_mfma_f32_16x16x32_bf16(qf[m], bk[n],  Pa[m][n], 0, 0, 0);
      }
  }

  float emi[16];
#pragma unroll
  for (int m = 0; m < 4; ++m)
#pragma unroll
    for (int r2 = 0; r2 < 4; ++r2)
      emi[(m << 2) + r2] = __expf(-s * (float)((wr << 6) + (m << 4) + (lk << 2) + r2));
  const float lam1 = __expf(-s);
  float epj[4];
#pragma unroll
  for (int n = 0; n < 4; ++n)
    epj[n] = __expf(s * (float)((wc << 6) + (n << 4) + lr));

#pragma unroll
  for (int m = 0; m < 4; ++m)
#pragma unroll
    for (int n = 0; n < 4; ++n) {
      const int j = (wc << 6) + (n << 4) + lr;
#pragma unroll
      for (int r2 = 0; r2 < 4; ++r2) {
        const int i = (wr << 6) + (m << 4) + (lk << 2) + r2;
        Oa[m][n][r2] *= emi[(m << 2) + r2] * lam1;
        float pv = Pa[m][n][r2] * emi[(m << 2) + r2] * epj[n];
        Pa[m][n][r2] = (i >= j) ? pv : 0.f;
      }
    }
  __syncthreads();

#pragma unroll
  for (int m = 0; m < 4; ++m)
#pragma unroll
    for (int n = 0; n < 4; ++n) {
      const int j = (wc << 6) + (n << 4) + lr;
#pragma unroll
      for (int r2 = 0; r2 < 4; ++r2) {
        const int i = (wr << 6) + (m << 4) + (lk << 2) + r2;
        const int sl = (j >> 3) ^ (i & 15);
        Ks[(i << 7) + (sl << 3) + (j & 7)] = f2b(Pa[m][n][r2]);
      }
    }
  __syncthreads();

#pragma unroll
  for (int kt = 0; kt < 4; ++kt) {
    short8 pf[4], vf[4];
#pragma unroll
    for (int m = 0; m < 4; ++m) pf[m] = FRAG(Ks,  (wr << 6) + (m << 4) + lr, kt);
#pragma unroll
    for (int n = 0; n < 4; ++n) vf[n] = FRAG(VTs, (wc << 6) + (n << 4) + lr, kt);
#pragma unroll
    for (int m = 0; m < 4; ++m)
#pragma unroll
      for (int n = 0; n < 4; ++n)
        Oa[m][n] = __builtin_amdgcn_mfma_f32_16x16x32_bf16(pf[m], vf[n], Oa[m][n], 0, 0, 0);
  }

#pragma unroll
  for (int m = 0; m < 4; ++m)
#pragma unroll
    for (int n = 0; n < 4; ++n) {
      const int c = (wc << 6) + (n << 4) + lr;
#pragma unroll
      for (int r2 = 0; r2 < 4; ++r2) {
        const int i = (wr << 6) + (m << 4) + (lk << 2) + r2;
        attn[(((size_t)((b << 11) + (cc << 7) + i)) << 11) + (h << 7) + c] = Oa[m][n][r2];
      }
    }
}

// ---------------- RMSNorm * norm_w * sigmoid-gate -> bf16 ----------------
__global__ __launch_bounds__(256)
void norm_gate(const float* __restrict__ attn, const unsigned short* __restrict__ gateb,
               const float* __restrict__ normw, unsigned short* __restrict__ ybuf)
{
  const int row = blockIdx.x;
  const int tid = threadIdx.x;
  const float* ar = attn + ((size_t)row << 11);
  float4 v0 = *(const float4*)&ar[tid * 8];
  float4 v1 = *(const float4*)&ar[tid * 8 + 4];
  float ss = v0.x*v0.x + v0.y*v0.y + v0.z*v0.z + v0.w*v0.w
           + v1.x*v1.x + v1.y*v1.y + v1.z*v1.z + v1.w*v1.w;
#pragma unroll
  for (int off = 32; off > 0; off >>= 1) ss += __shfl_down(ss, off);
  __shared__ float red[4];
  if ((tid & 63) == 0) red[tid >> 6] = ss;
  __syncthreads();
  float tot = red[0] + red[1] + red[2] + red[3];
  float scale = rsqrtf(tot * (1.f / 2048.f) + 1e-6f);
  uint4 gg = *(const uint4*)&gateb[((size_t)row << 11) + tid * 8];
  float4 w0 = *(const float4*)&normw[tid * 8];
  float4 w1 = *(const float4*)&normw[tid * 8 + 4];
  ushort4 o0, o1;
  o0.x = f2b(v0.x * scale * w0.x * blo(gg.x));
  o0.y = f2b(v0.y * scale * w0.y * bhi(gg.x));
  o0.z = f2b(v0.z * scale * w0.z * blo(gg.y));
  o0.w = f2b(v0.w * scale * w0.w * bhi(gg.y));
  o1.x = f2b(v1.x * scale * w1.x * blo(gg.z));
  o1.y = f2b(v1.y * scale * w1.y * bhi(gg.z));
  o1.z = f2b(v1.z * scale * w1.z * blo(gg.w));
  o1.w = f2b(v1.w * scale * w1.w * bhi(gg.w));
  *(ushort4*)&ybuf[((size_t)row << 11) + tid * 8]     = o0;
  *(ushort4*)&ybuf[((size_t)row << 11) + tid * 8 + 4] = o1;
}

// ---------------------------------------------------------------------------
extern "C" void kernel_launch(void* const* d_in, const int* in_sizes, int n_in,
                              void* d_out, int out_size, void* d_ws, size_t ws_size,
                              hipStream_t stream)
{
  const float* x       = (const float*)d_in[0];
  const float* past_kv = (const float*)d_in[1];
  const float* slope   = (const float*)d_in[2];
  const float* w_qkv   = (const float*)d_in[3];
  const float* w_gate  = (const float*)d_in[4];
  const float* w_out   = (const float*)d_in[5];
  const float* norm_w  = (const float*)d_in[6];
  float* out    = (float*)d_out;
  float* out_kv = out + 8388608;
  if (ws_size < WS_NEED) return;
  char* ws = (char*)d_ws;
  unsigned short* xb     = (unsigned short*)(ws + OFF_XB);
  unsigned short* wqkvb  = (unsigned short*)(ws + OFF_WQKVB);
  unsigned short* wgateb = (unsigned short*)(ws + OFF_WGATEB);
  unsigned short* woutb  = (unsigned short*)(ws + OFF_WOUTB);
  unsigned short* qb     = (unsigned short*)(ws + OFF_QB);
  unsigned short* kb     = (unsigned short*)(ws + OFF_KB);
  unsigned short* vtb    = (unsigned short*)(ws + OFF_VTB);
  unsigned short* vrow   = (unsigned short*)(ws + OFF_ATTN);  // early lifetime
  unsigned short* ktb    = (unsigned short*)(ws + OFF_YBUF);  // early lifetime
  float*          kvc    = (float*)(ws + OFF_KVC);
  float*          attn   = (float*)(ws + OFF_ATTN);           // late lifetime
  unsigned short* gate   = (unsigned short*)(ws + OFF_GATE);
  unsigned short* ybuf   = (unsigned short*)(ws + OFF_YBUF);  // late lifetime

  cast_f2b<<<8192,  256, 0, stream>>>(x,      xb,     8388608);
  cast_f2b<<<12288, 256, 0, stream>>>(w_qkv,  wqkvb,  12582912);
  cast_f2b<<<4096,  256, 0, stream>>>(w_gate, wgateb, 4194304);
  cast_f2b<<<4096,  256, 0, stream>>>(w_out,  woutb,  4194304);

  // fused qkv+gate GEMM: B = [w_qkv ; w_gate] rows 0..8191 (contiguous in ws)
  gemm256_qkvg<<<512, 512, 0, stream>>>(xb, wqkvb, slope, qb, kb, vrow, gate);

  tkv<<<512, 256, 0, stream>>>(kb, vrow, slope, ktb, vtb);

  chunk_kv_mfma <<<512, 256, 0, stream>>>(vtb, ktb, kvc);
  combine_kv    <<<256, 256, 0, stream>>>(kvc, past_kv, slope, out_kv);
  chunk_out_mfma<<<512, 256, 0, stream>>>(qb, kb, vtb, kvc, slope, attn);

  norm_gate<<<4096, 256, 0, stream>>>(attn, gate, norm_w, ybuf);
  gemm_out<<<dim3(16, 32), 256, 0, stream>>>(ybuf, woutb, 2048, 2048, out);
}